// Round 14
// baseline (152.696 us; speedup 1.0000x reference)
//
#include <hip/hip_runtime.h>
#include <hip/hip_bf16.h>
#include <math.h>

#define TT 256   // seq len
#define DD 512   // d_model
#define NN 8     // heads
#define HH 64    // head dim
#define PROJ 131072

typedef __attribute__((ext_vector_type(8))) short short8v;   // 8 bf16
typedef __attribute__((ext_vector_type(4))) short short4v;   // 4 bf16
typedef __attribute__((ext_vector_type(4))) float f32x4;

__device__ __forceinline__ short f2bf(float x) {
    __hip_bfloat16 h = __float2bfloat16(x);   // RNE; pairs into v_cvt_pk_bf16_f32
    return *reinterpret_cast<short*>(&h);
}

#define LGKM0 asm volatile("s_waitcnt lgkmcnt(0)" ::: "memory")

// ---------------- workspace layout ----------------
// float region (floats)
#define F_NUM  0            // 131072
#define F_DEN  131072       // 2048
#define F_END  133120
// short region, base = (short*)(ws + F_END), offsets in shorts
#define S_PB   0            // 5*131072  (K1,K2,Q,V1,V2 bf16 [p][n][t][h])
#define S_XB   655360       // 131072    xb[t][d]
#define S_WB   786432       // 1310720   Wb[p][n][h][d]
#define S_KQB  2097152      // 2097152   Kqb[n][ij][k]
#define S_VQB  4194304      // 2097152   Vqb[n][h][i][j]
#define S_WOB  6291456      // 262144    WOb[d][nh]
#define S_S1B  6553600      // 8388608   S1b[n][r][ij]
#define S_AB   14942208     // 8388608   Ab[n][t][h*64+i]
#define S_GB   23330816     // 33554432  G[n][t][r][i]   (t-major, pre-scaled by 1/64)

// =============== prep: all converts + num/den zeroing in ONE dispatch =========
__global__ __launch_bounds__(256) void prep_kernel(
    const float* __restrict__ x, const float* __restrict__ W_Kq,
    const float* __restrict__ W0, const float* __restrict__ W1,
    const float* __restrict__ W2, const float* __restrict__ W3,
    const float* __restrict__ W4, const float* __restrict__ Vq,
    const float* __restrict__ WO, short* __restrict__ sb, float* __restrict__ fz)
{
    __shared__ float plds[64 * 129];
    int b = blockIdx.x;
    int tid = threadIdx.x;
    if (b < 1024) {                       // cvt W_Kq -> Kqb (natural layout)
        int i = b * 256 + tid;
        const float4 f0 = *(const float4*)(W_Kq + (size_t)i * 8);
        const float4 f1 = *(const float4*)(W_Kq + (size_t)i * 8 + 4);
        short8v o;
        o[0]=f2bf(f0.x); o[1]=f2bf(f0.y); o[2]=f2bf(f0.z); o[3]=f2bf(f0.w);
        o[4]=f2bf(f1.x); o[5]=f2bf(f1.y); o[6]=f2bf(f1.z); o[7]=f2bf(f1.w);
        *(short8v*)(sb + S_KQB + (size_t)i * 8) = o;
    } else if (b < 1088) {                // cvt x -> xb
        int i = (b - 1024) * 256 + tid;
        const float4 f0 = *(const float4*)(x + (size_t)i * 8);
        const float4 f1 = *(const float4*)(x + (size_t)i * 8 + 4);
        short8v o;
        o[0]=f2bf(f0.x); o[1]=f2bf(f0.y); o[2]=f2bf(f0.z); o[3]=f2bf(f0.w);
        o[4]=f2bf(f1.x); o[5]=f2bf(f1.y); o[6]=f2bf(f1.z); o[7]=f2bf(f1.w);
        *(short8v*)(sb + S_XB + (size_t)i * 8) = o;
    } else if (b < 1128) {                // Wb[p][n][h][d] <- W_p[n][d][h]
        int pn = b - 1088; int p = pn >> 3, n = pn & 7;
        const float* Wp = (p==0)?W0:(p==1)?W1:(p==2)?W2:(p==3)?W3:W4;
        const float* src = Wp + (size_t)n * DD * HH;
        short* dst = sb + S_WB + (size_t)pn * HH * DD;
        for (int d0 = 0; d0 < DD; d0 += 64) {
            __syncthreads();
            for (int it = 0; it < 16; ++it) {
                int m = it * 256 + tid;
                int dl = m >> 6, h = m & 63;
                plds[h * 65 + dl] = src[(size_t)(d0 + dl) * 64 + h];
            }
            __syncthreads();
            int h = tid >> 2, seg = tid & 3;
            short8v o0, o1;
            #pragma unroll
            for (int e = 0; e < 8; ++e) o0[e] = f2bf(plds[h * 65 + seg * 16 + e]);
            #pragma unroll
            for (int e = 0; e < 8; ++e) o1[e] = f2bf(plds[h * 65 + seg * 16 + 8 + e]);
            *(short8v*)(dst + (size_t)h * DD + d0 + seg * 16) = o0;
            *(short8v*)(dst + (size_t)h * DD + d0 + seg * 16 + 8) = o1;
        }
    } else if (b < 1640) {                // Vqb[n][h][i][j] <- W_Vq[n][i][j][h]
        int bb = b - 1128; int n = bb >> 6, i = bb & 63;
        const float* src = Vq + (size_t)(n * 64 + i) * 4096;
        for (int it = 0; it < 16; ++it) {
            int m = it * 256 + tid;
            int j = m >> 6, h = m & 63;
            plds[h * 65 + j] = src[(size_t)j * 64 + h];
        }
        __syncthreads();
        int h = tid >> 2, seg = tid & 3;
        short8v o0, o1;
        #pragma unroll
        for (int e = 0; e < 8; ++e) o0[e] = f2bf(plds[h * 65 + seg * 16 + e]);
        #pragma unroll
        for (int e = 0; e < 8; ++e) o1[e] = f2bf(plds[h * 65 + seg * 16 + 8 + e]);
        short* dst = sb + S_VQB + (size_t)n * 262144 + (size_t)h * 4096 + i * 64 + seg * 16;
        *(short8v*)dst = o0;
        *(short8v*)(dst + 8) = o1;
    } else if (b < 1672) {                // WOb[d][nh] <- W_O[nh][d]
        int bb = b - 1640; int dc = bb & 7, nhc = bb >> 3;
        for (int it = 0; it < 32; ++it) {
            int m = it * 256 + tid;
            int nhl = m >> 6, dl = m & 63;
            plds[dl * 129 + nhl] = WO[(size_t)(nhc * 128 + nhl) * 512 + dc * 64 + dl];
        }
        __syncthreads();
        for (int it = 0; it < 4; ++it) {
            int m = it * 256 + tid;
            int dl = m >> 4, seg = m & 15;
            short8v o;
            #pragma unroll
            for (int e = 0; e < 8; ++e) o[e] = f2bf(plds[dl * 129 + seg * 8 + e]);
            *(short8v*)(sb + S_WOB + (size_t)(dc * 64 + dl) * 512 + nhc * 128 + seg * 8) = o;
        }
    } else {                              // zero num+den (130 blocks x 1024 floats)
        int i = (b - 1672) * 1024 + tid * 4;
        *(float4*)(fz + i) = make_float4(0.f, 0.f, 0.f, 0.f);
    }
}

// ---------------- proj (MFMA): Pb[p][n][t][h] = xb[t][:] . Wb[p][n][h][:] + b --
__global__ __launch_bounds__(512) void proj_kernel(
    const short* __restrict__ xb, const short* __restrict__ Wb,
    const float* __restrict__ bK1, const float* __restrict__ bK2,
    const float* __restrict__ bQ,  const float* __restrict__ bV1,
    const float* __restrict__ bV2, short* __restrict__ Pb) {
    int p = blockIdx.x, n = blockIdx.y, mhalf = blockIdx.z;
    int wv = threadIdx.x >> 6, lane = threadIdx.x & 63, g = lane >> 4, c = lane & 15;
    __shared__ short wlds[64 * 520];
    __shared__ short sbuf[8][16 * 72];
    const short* wsrc = Wb + (size_t)(p * 8 + n) * HH * DD;
    for (int it = 0; it < 8; ++it) {
        int idx = it * 512 + threadIdx.x;
        int h = idx >> 6, seg = idx & 63;
        *(short8v*)(&wlds[h * 520 + seg * 8]) = *(const short8v*)(wsrc + (size_t)h * DD + seg * 8);
    }
    __syncthreads();
    int mt = mhalf * 8 + wv;
    f32x4 acc[4];
    #pragma unroll
    for (int ct = 0; ct < 4; ++ct) acc[ct] = (f32x4){0.f, 0.f, 0.f, 0.f};
    for (int ks = 0; ks < 16; ++ks) {
        short8v a = *(const short8v*)(xb + (size_t)(mt * 16 + c) * DD + ks * 32 + g * 8);
        #pragma unroll
        for (int ct = 0; ct < 4; ++ct) {
            short8v b = *(const short8v*)(&wlds[(ct * 16 + c) * 520 + ks * 32 + g * 8]);
            acc[ct] = __builtin_amdgcn_mfma_f32_16x16x32_bf16(a, b, acc[ct], 0, 0, 0);
        }
    }
    const float* bp = (p == 0) ? bK1 : (p == 1) ? bK2 : (p == 2) ? bQ : (p == 3) ? bV1 : bV2;
    short* sbw = &sbuf[wv][0];
    #pragma unroll
    for (int ct = 0; ct < 4; ++ct) {
        float bias = bp[n * 64 + ct * 16 + c];
        #pragma unroll
        for (int m = 0; m < 4; ++m)
            sbw[(g * 4 + m) * 72 + ct * 16 + c] = f2bf(acc[ct][m] + bias);
    }
    LGKM0;
    int rl = lane & 15, sg = lane >> 4;
    short8v o0 = *(const short8v*)(&sbw[rl * 72 + sg * 16]);
    short8v o1 = *(const short8v*)(&sbw[rl * 72 + sg * 16 + 8]);
    short* dst = Pb + (size_t)p * PROJ + (size_t)(n * 256 + mt * 16 + rl) * 64 + sg * 16;
    *(short8v*)dst = o0;
    *(short8v*)(dst + 8) = o1;
}

// ------ merged batch GEMM: z<4 -> step1 (A0,B0,O0), z>=4 -> Ab (A1,B1,O1) ------
__global__ __launch_bounds__(256) void bgemm_kernel(
    const short* __restrict__ A0, const short* __restrict__ B0, short* __restrict__ O0,
    const short* __restrict__ A1, const short* __restrict__ B1, short* __restrict__ O1) {
    int mt = blockIdx.x, n = blockIdx.y, z = blockIdx.z;
    const short* A = (z < 4) ? A0 : A1;
    const short* B = (z < 4) ? B0 : B1;
    short* out = (z < 4) ? O0 : O1;
    int cgq = z & 3;
    int wv = threadIdx.x >> 6, lane = threadIdx.x & 63, g = lane >> 4, c = lane & 15;
    __shared__ short sbuf[4][16 * 72];
    short* sbw = &sbuf[wv][0];
    const short* abase = A + ((size_t)n * 256 + mt * 16 + c) * 64 + g * 8;
    short8v a0 = *(const short8v*)abase;
    short8v a1 = *(const short8v*)(abase + 32);
    for (int cg = cgq * 16 + wv; cg < cgq * 16 + 16; cg += 4) {
        f32x4 acc[4];
        #pragma unroll
        for (int jt = 0; jt < 4; ++jt) acc[jt] = (f32x4){0.f, 0.f, 0.f, 0.f};
        const short* bb = B + ((size_t)n * 4096 + cg * 64) * 64;
        #pragma unroll
        for (int jt = 0; jt < 4; ++jt) {
            short8v b0 = *(const short8v*)(bb + (size_t)(jt * 16 + c) * 64 + g * 8);
            short8v b1 = *(const short8v*)(bb + (size_t)(jt * 16 + c) * 64 + g * 8 + 32);
            acc[jt] = __builtin_amdgcn_mfma_f32_16x16x32_bf16(a0, b0, acc[jt], 0, 0, 0);
            acc[jt] = __builtin_amdgcn_mfma_f32_16x16x32_bf16(a1, b1, acc[jt], 0, 0, 0);
        }
        LGKM0;
        #pragma unroll
        for (int jt = 0; jt < 4; ++jt)
            #pragma unroll
            for (int m = 0; m < 4; ++m)
                sbw[(g * 4 + m) * 72 + jt * 16 + c] = f2bf(acc[jt][m]);
        LGKM0;
        int rl = lane & 15, sg = lane >> 4;
        short8v o0 = *(const short8v*)(&sbw[rl * 72 + sg * 16]);
        short8v o1 = *(const short8v*)(&sbw[rl * 72 + sg * 16 + 8]);
        short* dst = out + ((size_t)n * 256 + mt * 16 + rl) * 4096 + cg * 64 + sg * 16;
        *(short8v*)dst = o0;
        *(short8v*)(dst + 8) = o1;
    }
}

// ---------- G[n][t][r][i] = (1/64) sum_j S1[n][r][i][j]*k2[n][t][j] ------------
__global__ __launch_bounds__(256) void gmat_kernel(const short* __restrict__ S1b,
                                                   const short* __restrict__ K2b,
                                                   short* __restrict__ G) {
    int bid = blockIdx.x;
    int n = bid & 7;
    int tt = (bid >> 3) & 15;
    int rq = bid >> 7;
    int wv = threadIdx.x >> 6, lane = threadIdx.x & 63, g = lane >> 4, c = lane & 15;
    int t0 = tt * 16;
    __shared__ short sbuf[4][16 * 68];
    short* sbw = &sbuf[wv][0];
    const short* abase = K2b + ((size_t)n * TT + t0 + c) * 64 + g * 8;
    short8v a0 = *(const short8v*)abase;
    short8v a1 = *(const short8v*)(abase + 32);
    for (int r = t0 + rq * 4 + wv; r < 256; r += 16) {
        const short* bb = S1b + ((size_t)(n * 256 + r) * 64) * 64;
        f32x4 acc[4];
        #pragma unroll
        for (int it = 0; it < 4; ++it) {
            short8v b0 = *(const short8v*)(bb + (size_t)(it * 16 + c) * 64 + g * 8);
            short8v b1 = *(const short8v*)(bb + (size_t)(it * 16 + c) * 64 + g * 8 + 32);
            acc[it] = (f32x4){0.f, 0.f, 0.f, 0.f};
            acc[it] = __builtin_amdgcn_mfma_f32_16x16x32_bf16(a0, b0, acc[it], 0, 0, 0);
            acc[it] = __builtin_amdgcn_mfma_f32_16x16x32_bf16(a1, b1, acc[it], 0, 0, 0);
        }
        LGKM0;   // previous iteration's sbuf reads complete
        #pragma unroll
        for (int it = 0; it < 4; ++it)
            #pragma unroll
            for (int m = 0; m < 4; ++m)
                sbw[(g * 4 + m) * 68 + it * 16 + c] = f2bf(acc[it][m] * 0.015625f);
        LGKM0;
        int trow = lane >> 2, seg = (lane & 3) * 16;
        short8v o0 = *(const short8v*)(&sbw[trow * 68 + seg]);
        short8v o1 = *(const short8v*)(&sbw[trow * 68 + seg + 8]);
        short* dst = G + (((size_t)(n * TT + t0 + trow)) * TT + r) * 64 + seg;
        *(short8v*)dst = o0;
        *(short8v*)(dst + 8) = o1;
    }
}

// ---------- fused cubic attention: barrier-free, 16 waves/block ---------------
// grid 512: n=bid&7 (XCD affinity), rt=(bid>>3)&15, tq=bid>>7 (0..3).
// 16 waves; wave wv handles t in {tq+4wv, +64, +128, +192} with t <= rt*16+14.
// k1/v1 staged to LDS once (1 barrier total). U tiles computed in-register by
// the consuming wave (C-frag of mfma(v1,Ab) == B-frag of PV mfma_1k).
__global__ __launch_bounds__(1024) void attn_kernel(
    const short* __restrict__ K1b, const short* __restrict__ V1b,
    const short* __restrict__ Gm, const short* __restrict__ Ab,
    float* __restrict__ num, float* __restrict__ den)
{
    int bid = blockIdx.x;
    int n = bid & 7;
    int rt = (bid >> 3) & 15;
    int tq = bid >> 7;            // 0..3
    int tid = threadIdx.x;
    int wv = tid >> 6, lane = tid & 63, g = lane >> 4, c = lane & 15;

    __shared__ short k1lds[256 * 72];   // 36.9 KB
    __shared__ short v1lds[256 * 72];   // 36.9 KB

    int tmax = rt * 16 + 14;
    if (tmax > 254) tmax = 254;
    int rows = (rt + 1) * 16;           // s <= tmax-1 -> s-tiles 0..rt
    if (rows > 256) rows = 256;

    for (int idx = tid; idx < rows * 8; idx += 1024) {
        int row = idx >> 3, seg = idx & 7;
        *(short8v*)(&k1lds[row * 72 + seg * 8]) =
            *(const short8v*)(K1b + ((size_t)n * TT + row) * 64 + seg * 8);
        *(short8v*)(&v1lds[row * 72 + seg * 8]) =
            *(const short8v*)(V1b + ((size_t)n * TT + row) * 64 + seg * 8);
    }
    __syncthreads();   // the only barrier

    f32x4 numacc[4];
    #pragma unroll
    for (int b = 0; b < 4; ++b) numacc[b] = (f32x4){0.f, 0.f, 0.f, 0.f};
    float denacc = 0.f;
    int r = rt * 16 + c;

    for (int t = tq + 4 * wv; t <= tmax; t += 64) {
        if (t < 1) continue;            // only the t==0 slot
        int cntU = ((t - 1) >> 4) + 1;  // 1..16 s-tiles

        // Ab[t] fragments (4 h-tiles) and G[t][rt] fragment, from L2
        short8v ab0[4], ab1[4];
        #pragma unroll
        for (int hs = 0; hs < 4; ++hs) {
            const short* ar = Ab + (size_t)(n * TT + t) * 4096 + (hs * 16 + c) * 64 + g * 8;
            ab0[hs] = *(const short8v*)ar;
            ab1[hs] = *(const short8v*)(ar + 32);
        }
        const short* gb = Gm + (((size_t)(n * TT + t) * TT) + rt * 16 + c) * 64 + g * 8;
        short8v gf0 = *(const short8v*)gb;
        short8v gf1 = *(const short8v*)(gb + 32);

        for (int loc = 0; loc < cntU; ++loc) {
            // U tiles for this s-tile, all 4 h-tiles, in-register
            const short* vr = &v1lds[(loc * 16 + c) * 72 + g * 8];
            short8v vf0 = *(const short8v*)vr;
            short8v vf1 = *(const short8v*)(vr + 32);
            short4v ub[4];
            #pragma unroll
            for (int hs = 0; hs < 4; ++hs) {
                f32x4 u = (f32x4){0.f, 0.f, 0.f, 0.f};
                u = __builtin_amdgcn_mfma_f32_16x16x32_bf16(vf0, ab0[hs], u, 0, 0, 0);
                u = __builtin_amdgcn_mfma_f32_16x16x32_bf16(vf1, ab1[hs], u, 0, 0, 0);
                #pragma unroll
                for (int m = 0; m < 4; ++m) ub[hs][m] = f2bf(u[m]);
            }
            // logits
            const short* kr = &k1lds[(loc * 16 + c) * 72 + g * 8];
            short8v af0 = *(const short8v*)kr;
            short8v af1 = *(const short8v*)(kr + 32);
            f32x4 lg = (f32x4){0.f, 0.f, 0.f, 0.f};
            lg = __builtin_amdgcn_mfma_f32_16x16x32_bf16(af0, gf0, lg, 0, 0, 0);
            lg = __builtin_amdgcn_mfma_f32_16x16x32_bf16(af1, gf1, lg, 0, 0, 0);
            int s_base = loc * 16;
            short4v eb;
            float dsum = 0.f;
            #pragma unroll
            for (int m = 0; m < 4; ++m) {
                int s = s_base + g * 4 + m;
                float e = (s < t && r > t) ? __expf(lg[m]) : 0.f;   // G pre-scaled 1/64
                dsum += e;
                eb[m] = f2bf(e);
            }
            denacc += dsum;
            #pragma unroll
            for (int hs = 0; hs < 4; ++hs)
                numacc[hs] = __builtin_amdgcn_mfma_f32_16x16x16bf16_1k(eb, ub[hs], numacc[hs], 0, 0, 0);
        }
    }

    // epilogue: skip entirely if this wave never produced a contribution
    if (__any(denacc != 0.f)) {
        float v = denacc;
        v += __shfl_xor(v, 16);
        v += __shfl_xor(v, 32);
        if (lane < 16) atomicAdd(&den[n * TT + rt * 16 + lane], v);
        #pragma unroll
        for (int hs = 0; hs < 4; ++hs)
            #pragma unroll
            for (int m = 0; m < 4; ++m)
                atomicAdd(&num[((size_t)(n * TT + rt * 16 + g * 4 + m)) * 64 + hs * 16 + c],
                          numacc[hs][m]);
    }
}

// ---------- out[t][d] = b_O[d] + (num/den)[t][:] . WOb[d][:]  (fused zdiv) -----
__global__ __launch_bounds__(512) void out_kernel(const float* __restrict__ num,
                                                  const float* __restrict__ den,
                                                  const short* __restrict__ WOb,
                                                  const float* __restrict__ bO,
                                                  float* __restrict__ out) {
    int mt = blockIdx.x & 15, dq = blockIdx.x >> 4;
    int wv = threadIdx.x >> 6, lane = threadIdx.x & 63, g = lane >> 4, c = lane & 15;
    int dt0 = dq * 16 + wv * 2;
    int t = mt * 16 + c;
    f32x4 acc[2];
    acc[0] = (f32x4){0.f, 0.f, 0.f, 0.f};
    acc[1] = (f32x4){0.f, 0.f, 0.f, 0.f};
    for (int ks = 0; ks < 16; ++ks) {
        int nh = ks * 32 + g * 8;
        int nn = nh >> 6, h = nh & 63;
        float dv = den[nn * 256 + t];
        float rcp = (dv > 0.f) ? 1.f / dv : 0.f;
        const float* np = num + ((size_t)(nn * 256 + t) * 64 + h);
        float4 f0 = *(const float4*)np;
        float4 f1 = *(const float4*)(np + 4);
        short8v a;
        a[0]=f2bf(f0.x*rcp); a[1]=f2bf(f0.y*rcp); a[2]=f2bf(f0.z*rcp); a[3]=f2bf(f0.w*rcp);
        a[4]=f2bf(f1.x*rcp); a[5]=f2bf(f1.y*rcp); a[6]=f2bf(f1.z*rcp); a[7]=f2bf(f1.w*rcp);
        #pragma unroll
        for (int u = 0; u < 2; ++u) {
            short8v b = *(const short8v*)(WOb + (size_t)((dt0 + u) * 16 + c) * 512 + ks * 32 + g * 8);
            acc[u] = __builtin_amdgcn_mfma_f32_16x16x32_bf16(a, b, acc[u], 0, 0, 0);
        }
    }
    #pragma unroll
    for (int u = 0; u < 2; ++u) {
        int d = (dt0 + u) * 16 + c;
        float bias = bO[d];
        #pragma unroll
        for (int m = 0; m < 4; ++m)
            out[(size_t)(mt * 16 + g * 4 + m) * 512 + d] = acc[u][m] + bias;
    }
}

extern "C" void kernel_launch(void* const* d_in, const int* in_sizes, int n_in,
                              void* d_out, int out_size, void* d_ws, size_t ws_size,
                              hipStream_t stream) {
    const float* x    = (const float*)d_in[0];
    const float* W_K1 = (const float*)d_in[1];
    const float* W_K2 = (const float*)d_in[2];
    const float* W_Q  = (const float*)d_in[3];
    const float* W_V1 = (const float*)d_in[4];
    const float* W_V2 = (const float*)d_in[5];
    const float* W_Kq = (const float*)d_in[6];
    const float* W_Vq = (const float*)d_in[7];
    const float* W_O  = (const float*)d_in[8];
    const float* b_K1 = (const float*)d_in[9];
    const float* b_K2 = (const float*)d_in[10];
    const float* b_Q  = (const float*)d_in[11];
    const float* b_V1 = (const float*)d_in[12];
    const float* b_V2 = (const float*)d_in[13];
    const float* b_O  = (const float*)d_in[14];
    float* ws = (float*)d_ws;
    short* sb = (short*)(ws + F_END);
    float* out = (float*)d_out;

    // all converts + num/den zeroing
    prep_kernel<<<1802, 256, 0, stream>>>(x, W_Kq, W_K1, W_K2, W_Q, W_V1, W_V2,
                                          W_Vq, W_O, sb, ws + F_NUM);

    // projections (bf16)
    proj_kernel<<<dim3(5, 8, 2), 512, 0, stream>>>(sb + S_XB, sb + S_WB,
                                                   b_K1, b_K2, b_Q, b_V1, b_V2, sb + S_PB);

    // step1[n][r][ij] and Ab[n][t][hi] in one dispatch
    bgemm_kernel<<<dim3(16, 8, 8), 256, 0, stream>>>(
        sb + S_PB + 2 * PROJ, sb + S_KQB, sb + S_S1B,
        sb + S_PB + 4 * PROJ, sb + S_VQB, sb + S_AB);

    // G in [n][t][r][i], coalesced stores, pre-scaled by 1/64
    gmat_kernel<<<512, 256, 0, stream>>>(sb + S_S1B, sb + S_PB + 1 * PROJ, sb + S_GB);

    // fused cubic attention (barrier-free, 16 waves/block)
    attn_kernel<<<512, 1024, 0, stream>>>(sb + S_PB, sb + S_PB + 3 * PROJ,
                                          sb + S_GB, sb + S_AB,
                                          ws + F_NUM, ws + F_DEN);

    // output projection with fused zdiv
    out_kernel<<<32, 512, 0, stream>>>(ws + F_NUM, ws + F_DEN, sb + S_WOB, b_O, out);
}

// Round 15
// 137.518 us; speedup vs baseline: 1.1104x; 1.1104x over previous
//
#include <hip/hip_runtime.h>
#include <hip/hip_bf16.h>
#include <math.h>

#define TT 256   // seq len
#define DD 512   // d_model
#define NN 8     // heads
#define HH 64    // head dim
#define PROJ 131072

typedef __attribute__((ext_vector_type(8))) short short8v;   // 8 bf16
typedef __attribute__((ext_vector_type(4))) short short4v;   // 4 bf16
typedef __attribute__((ext_vector_type(4))) float f32x4;

__device__ __forceinline__ short f2bf(float x) {
    __hip_bfloat16 h = __float2bfloat16(x);   // RNE; pairs into v_cvt_pk_bf16_f32
    return *reinterpret_cast<short*>(&h);
}

#define LGKM0 asm volatile("s_waitcnt lgkmcnt(0)" ::: "memory")

// ---------------- workspace layout ----------------
// float region (floats)
#define F_NUM  0            // 131072
#define F_DEN  131072       // 2048
#define F_END  133120
// short region, base = (short*)(ws + F_END), offsets in shorts
#define S_PB   0            // 5*131072  (K1,K2,Q,V1,V2 bf16 [p][n][t][h])
#define S_XB   655360       // 131072    xb[t][d]
#define S_WB   786432       // 1310720   Wb[p][n][h][d]
#define S_KQB  2097152      // 2097152   Kqb[n][ij][k]
#define S_VQB  4194304      // 2097152   Vqb[n][h][i][j]
#define S_WOB  6291456      // 262144    WOb[d][nh]
#define S_S1B  6553600      // 8388608   S1b[n][r][ij]
#define S_AB   14942208     // 8388608   Ab[n][t][h*64+i]
#define S_GB   23330816     // 33554432  G[n][t][r][i]   (t-major, pre-scaled by 1/64)

// =============== prep: all converts + num/den zeroing in ONE dispatch =========
__global__ __launch_bounds__(256) void prep_kernel(
    const float* __restrict__ x, const float* __restrict__ W_Kq,
    const float* __restrict__ W0, const float* __restrict__ W1,
    const float* __restrict__ W2, const float* __restrict__ W3,
    const float* __restrict__ W4, const float* __restrict__ Vq,
    const float* __restrict__ WO, short* __restrict__ sb, float* __restrict__ fz)
{
    __shared__ float plds[64 * 129];
    int b = blockIdx.x;
    int tid = threadIdx.x;
    if (b < 1024) {                       // cvt W_Kq -> Kqb (natural layout)
        int i = b * 256 + tid;
        const float4 f0 = *(const float4*)(W_Kq + (size_t)i * 8);
        const float4 f1 = *(const float4*)(W_Kq + (size_t)i * 8 + 4);
        short8v o;
        o[0]=f2bf(f0.x); o[1]=f2bf(f0.y); o[2]=f2bf(f0.z); o[3]=f2bf(f0.w);
        o[4]=f2bf(f1.x); o[5]=f2bf(f1.y); o[6]=f2bf(f1.z); o[7]=f2bf(f1.w);
        *(short8v*)(sb + S_KQB + (size_t)i * 8) = o;
    } else if (b < 1088) {                // cvt x -> xb
        int i = (b - 1024) * 256 + tid;
        const float4 f0 = *(const float4*)(x + (size_t)i * 8);
        const float4 f1 = *(const float4*)(x + (size_t)i * 8 + 4);
        short8v o;
        o[0]=f2bf(f0.x); o[1]=f2bf(f0.y); o[2]=f2bf(f0.z); o[3]=f2bf(f0.w);
        o[4]=f2bf(f1.x); o[5]=f2bf(f1.y); o[6]=f2bf(f1.z); o[7]=f2bf(f1.w);
        *(short8v*)(sb + S_XB + (size_t)i * 8) = o;
    } else if (b < 1128) {                // Wb[p][n][h][d] <- W_p[n][d][h]
        int pn = b - 1088; int p = pn >> 3, n = pn & 7;
        const float* Wp = (p==0)?W0:(p==1)?W1:(p==2)?W2:(p==3)?W3:W4;
        const float* src = Wp + (size_t)n * DD * HH;
        short* dst = sb + S_WB + (size_t)pn * HH * DD;
        for (int d0 = 0; d0 < DD; d0 += 64) {
            __syncthreads();
            for (int it = 0; it < 16; ++it) {
                int m = it * 256 + tid;
                int dl = m >> 6, h = m & 63;
                plds[h * 65 + dl] = src[(size_t)(d0 + dl) * 64 + h];
            }
            __syncthreads();
            int h = tid >> 2, seg = tid & 3;
            short8v o0, o1;
            #pragma unroll
            for (int e = 0; e < 8; ++e) o0[e] = f2bf(plds[h * 65 + seg * 16 + e]);
            #pragma unroll
            for (int e = 0; e < 8; ++e) o1[e] = f2bf(plds[h * 65 + seg * 16 + 8 + e]);
            *(short8v*)(dst + (size_t)h * DD + d0 + seg * 16) = o0;
            *(short8v*)(dst + (size_t)h * DD + d0 + seg * 16 + 8) = o1;
        }
    } else if (b < 1640) {                // Vqb[n][h][i][j] <- W_Vq[n][i][j][h]
        int bb = b - 1128; int n = bb >> 6, i = bb & 63;
        const float* src = Vq + (size_t)(n * 64 + i) * 4096;
        for (int it = 0; it < 16; ++it) {
            int m = it * 256 + tid;
            int j = m >> 6, h = m & 63;
            plds[h * 65 + j] = src[(size_t)j * 64 + h];
        }
        __syncthreads();
        int h = tid >> 2, seg = tid & 3;
        short8v o0, o1;
        #pragma unroll
        for (int e = 0; e < 8; ++e) o0[e] = f2bf(plds[h * 65 + seg * 16 + e]);
        #pragma unroll
        for (int e = 0; e < 8; ++e) o1[e] = f2bf(plds[h * 65 + seg * 16 + 8 + e]);
        short* dst = sb + S_VQB + (size_t)n * 262144 + (size_t)h * 4096 + i * 64 + seg * 16;
        *(short8v*)dst = o0;
        *(short8v*)(dst + 8) = o1;
    } else if (b < 1672) {                // WOb[d][nh] <- W_O[nh][d]
        int bb = b - 1640; int dc = bb & 7, nhc = bb >> 3;
        for (int it = 0; it < 32; ++it) {
            int m = it * 256 + tid;
            int nhl = m >> 6, dl = m & 63;
            plds[dl * 129 + nhl] = WO[(size_t)(nhc * 128 + nhl) * 512 + dc * 64 + dl];
        }
        __syncthreads();
        for (int it = 0; it < 4; ++it) {
            int m = it * 256 + tid;
            int dl = m >> 4, seg = m & 15;
            short8v o;
            #pragma unroll
            for (int e = 0; e < 8; ++e) o[e] = f2bf(plds[dl * 129 + seg * 8 + e]);
            *(short8v*)(sb + S_WOB + (size_t)(dc * 64 + dl) * 512 + nhc * 128 + seg * 8) = o;
        }
    } else {                              // zero num+den (130 blocks x 1024 floats)
        int i = (b - 1672) * 1024 + tid * 4;
        *(float4*)(fz + i) = make_float4(0.f, 0.f, 0.f, 0.f);
    }
}

// ---------------- proj (MFMA): Pb[p][n][t][h] = xb[t][:] . Wb[p][n][h][:] + b --
__global__ __launch_bounds__(512) void proj_kernel(
    const short* __restrict__ xb, const short* __restrict__ Wb,
    const float* __restrict__ bK1, const float* __restrict__ bK2,
    const float* __restrict__ bQ,  const float* __restrict__ bV1,
    const float* __restrict__ bV2, short* __restrict__ Pb) {
    int p = blockIdx.x, n = blockIdx.y, mhalf = blockIdx.z;
    int wv = threadIdx.x >> 6, lane = threadIdx.x & 63, g = lane >> 4, c = lane & 15;
    __shared__ short wlds[64 * 520];
    __shared__ short sbuf[8][16 * 72];
    const short* wsrc = Wb + (size_t)(p * 8 + n) * HH * DD;
    for (int it = 0; it < 8; ++it) {
        int idx = it * 512 + threadIdx.x;
        int h = idx >> 6, seg = idx & 63;
        *(short8v*)(&wlds[h * 520 + seg * 8]) = *(const short8v*)(wsrc + (size_t)h * DD + seg * 8);
    }
    __syncthreads();
    int mt = mhalf * 8 + wv;
    f32x4 acc[4];
    #pragma unroll
    for (int ct = 0; ct < 4; ++ct) acc[ct] = (f32x4){0.f, 0.f, 0.f, 0.f};
    for (int ks = 0; ks < 16; ++ks) {
        short8v a = *(const short8v*)(xb + (size_t)(mt * 16 + c) * DD + ks * 32 + g * 8);
        #pragma unroll
        for (int ct = 0; ct < 4; ++ct) {
            short8v b = *(const short8v*)(&wlds[(ct * 16 + c) * 520 + ks * 32 + g * 8]);
            acc[ct] = __builtin_amdgcn_mfma_f32_16x16x32_bf16(a, b, acc[ct], 0, 0, 0);
        }
    }
    const float* bp = (p == 0) ? bK1 : (p == 1) ? bK2 : (p == 2) ? bQ : (p == 3) ? bV1 : bV2;
    short* sbw = &sbuf[wv][0];
    #pragma unroll
    for (int ct = 0; ct < 4; ++ct) {
        float bias = bp[n * 64 + ct * 16 + c];
        #pragma unroll
        for (int m = 0; m < 4; ++m)
            sbw[(g * 4 + m) * 72 + ct * 16 + c] = f2bf(acc[ct][m] + bias);
    }
    LGKM0;
    int rl = lane & 15, sg = lane >> 4;
    short8v o0 = *(const short8v*)(&sbw[rl * 72 + sg * 16]);
    short8v o1 = *(const short8v*)(&sbw[rl * 72 + sg * 16 + 8]);
    short* dst = Pb + (size_t)p * PROJ + (size_t)(n * 256 + mt * 16 + rl) * 64 + sg * 16;
    *(short8v*)dst = o0;
    *(short8v*)(dst + 8) = o1;
}

// ------ merged batch GEMM: z<4 -> step1 (A0,B0,O0), z>=4 -> Ab (A1,B1,O1) ------
__global__ __launch_bounds__(256) void bgemm_kernel(
    const short* __restrict__ A0, const short* __restrict__ B0, short* __restrict__ O0,
    const short* __restrict__ A1, const short* __restrict__ B1, short* __restrict__ O1) {
    int mt = blockIdx.x, n = blockIdx.y, z = blockIdx.z;
    const short* A = (z < 4) ? A0 : A1;
    const short* B = (z < 4) ? B0 : B1;
    short* out = (z < 4) ? O0 : O1;
    int cgq = z & 3;
    int wv = threadIdx.x >> 6, lane = threadIdx.x & 63, g = lane >> 4, c = lane & 15;
    __shared__ short sbuf[4][16 * 72];
    short* sbw = &sbuf[wv][0];
    const short* abase = A + ((size_t)n * 256 + mt * 16 + c) * 64 + g * 8;
    short8v a0 = *(const short8v*)abase;
    short8v a1 = *(const short8v*)(abase + 32);
    for (int cg = cgq * 16 + wv; cg < cgq * 16 + 16; cg += 4) {
        f32x4 acc[4];
        #pragma unroll
        for (int jt = 0; jt < 4; ++jt) acc[jt] = (f32x4){0.f, 0.f, 0.f, 0.f};
        const short* bb = B + ((size_t)n * 4096 + cg * 64) * 64;
        #pragma unroll
        for (int jt = 0; jt < 4; ++jt) {
            short8v b0 = *(const short8v*)(bb + (size_t)(jt * 16 + c) * 64 + g * 8);
            short8v b1 = *(const short8v*)(bb + (size_t)(jt * 16 + c) * 64 + g * 8 + 32);
            acc[jt] = __builtin_amdgcn_mfma_f32_16x16x32_bf16(a0, b0, acc[jt], 0, 0, 0);
            acc[jt] = __builtin_amdgcn_mfma_f32_16x16x32_bf16(a1, b1, acc[jt], 0, 0, 0);
        }
        LGKM0;
        #pragma unroll
        for (int jt = 0; jt < 4; ++jt)
            #pragma unroll
            for (int m = 0; m < 4; ++m)
                sbw[(g * 4 + m) * 72 + jt * 16 + c] = f2bf(acc[jt][m]);
        LGKM0;
        int rl = lane & 15, sg = lane >> 4;
        short8v o0 = *(const short8v*)(&sbw[rl * 72 + sg * 16]);
        short8v o1 = *(const short8v*)(&sbw[rl * 72 + sg * 16 + 8]);
        short* dst = out + ((size_t)n * 256 + mt * 16 + rl) * 4096 + cg * 64 + sg * 16;
        *(short8v*)dst = o0;
        *(short8v*)(dst + 8) = o1;
    }
}

// ---------- G[n][t][r][i] = (1/64) sum_j S1[n][r][i][j]*k2[n][t][j] ------------
__global__ __launch_bounds__(256) void gmat_kernel(const short* __restrict__ S1b,
                                                   const short* __restrict__ K2b,
                                                   short* __restrict__ G) {
    int bid = blockIdx.x;
    int n = bid & 7;
    int tt = (bid >> 3) & 15;
    int rq = bid >> 7;
    int wv = threadIdx.x >> 6, lane = threadIdx.x & 63, g = lane >> 4, c = lane & 15;
    int t0 = tt * 16;
    __shared__ short sbuf[4][16 * 68];
    short* sbw = &sbuf[wv][0];
    const short* abase = K2b + ((size_t)n * TT + t0 + c) * 64 + g * 8;
    short8v a0 = *(const short8v*)abase;
    short8v a1 = *(const short8v*)(abase + 32);
    for (int r = t0 + rq * 4 + wv; r < 256; r += 16) {
        const short* bb = S1b + ((size_t)(n * 256 + r) * 64) * 64;
        f32x4 acc[4];
        #pragma unroll
        for (int it = 0; it < 4; ++it) {
            short8v b0 = *(const short8v*)(bb + (size_t)(it * 16 + c) * 64 + g * 8);
            short8v b1 = *(const short8v*)(bb + (size_t)(it * 16 + c) * 64 + g * 8 + 32);
            acc[it] = (f32x4){0.f, 0.f, 0.f, 0.f};
            acc[it] = __builtin_amdgcn_mfma_f32_16x16x32_bf16(a0, b0, acc[it], 0, 0, 0);
            acc[it] = __builtin_amdgcn_mfma_f32_16x16x32_bf16(a1, b1, acc[it], 0, 0, 0);
        }
        LGKM0;   // previous iteration's sbuf reads complete
        #pragma unroll
        for (int it = 0; it < 4; ++it)
            #pragma unroll
            for (int m = 0; m < 4; ++m)
                sbw[(g * 4 + m) * 68 + it * 16 + c] = f2bf(acc[it][m] * 0.015625f);
        LGKM0;
        int trow = lane >> 2, seg = (lane & 3) * 16;
        short8v o0 = *(const short8v*)(&sbw[trow * 68 + seg]);
        short8v o1 = *(const short8v*)(&sbw[trow * 68 + seg + 8]);
        short* dst = G + (((size_t)(n * TT + t0 + trow)) * TT + r) * 64 + seg;
        *(short8v*)dst = o0;
        *(short8v*)(dst + 8) = o1;
    }
}

// ---------- fused cubic attention: barrier-free, complementary-rt pairing -----
// grid 512: n=bid&7 (XCD affinity), rtpair=(bid>>3)&7, tq=bid>>6 (0..7).
// Block handles rt_a=rtpair AND rt_b=15-rtpair sequentially -> per-block work
// proportional to (rt_a+1)+(rt_b+1)=17 (uniform). 8 waves; wave wv handles
// t in {tq+8wv+64k}. U tiles computed in-register by the consuming wave.
__global__ __launch_bounds__(512) void attn_kernel(
    const short* __restrict__ K1b, const short* __restrict__ V1b,
    const short* __restrict__ Gm, const short* __restrict__ Ab,
    float* __restrict__ num, float* __restrict__ den)
{
    int bid = blockIdx.x;
    int n = bid & 7;
    int rt_a = (bid >> 3) & 7;
    int rt_b = 15 - rt_a;
    int tq = bid >> 6;            // 0..7
    int tid = threadIdx.x;
    int wv = tid >> 6, lane = tid & 63, g = lane >> 4, c = lane & 15;

    __shared__ short k1lds[256 * 72];   // 36.9 KB
    __shared__ short v1lds[256 * 72];   // 36.9 KB

    int rows = (rt_b + 1) * 16;         // rt_b >= rt_a; covers both phases
    if (rows > 256) rows = 256;

    for (int idx = tid; idx < rows * 8; idx += 512) {
        int row = idx >> 3, seg = idx & 7;
        *(short8v*)(&k1lds[row * 72 + seg * 8]) =
            *(const short8v*)(K1b + ((size_t)n * TT + row) * 64 + seg * 8);
        *(short8v*)(&v1lds[row * 72 + seg * 8]) =
            *(const short8v*)(V1b + ((size_t)n * TT + row) * 64 + seg * 8);
    }
    __syncthreads();   // the only barrier

    #pragma unroll
    for (int phase = 0; phase < 2; ++phase) {
        int rt = phase ? rt_b : rt_a;
        int tmax = rt * 16 + 14;
        if (tmax > 254) tmax = 254;
        int r = rt * 16 + c;

        f32x4 numacc[4];
        #pragma unroll
        for (int b = 0; b < 4; ++b) numacc[b] = (f32x4){0.f, 0.f, 0.f, 0.f};
        float denacc = 0.f;

        for (int t = tq + 8 * wv; t <= tmax; t += 64) {
            if (t < 1) continue;
            int cntU = ((t - 1) >> 4) + 1;  // 1..16 s-tiles

            short8v ab0[4], ab1[4];
            #pragma unroll
            for (int hs = 0; hs < 4; ++hs) {
                const short* ar = Ab + (size_t)(n * TT + t) * 4096 + (hs * 16 + c) * 64 + g * 8;
                ab0[hs] = *(const short8v*)ar;
                ab1[hs] = *(const short8v*)(ar + 32);
            }
            const short* gb = Gm + (((size_t)(n * TT + t) * TT) + rt * 16 + c) * 64 + g * 8;
            short8v gf0 = *(const short8v*)gb;
            short8v gf1 = *(const short8v*)(gb + 32);

            for (int loc = 0; loc < cntU; ++loc) {
                const short* vr = &v1lds[(loc * 16 + c) * 72 + g * 8];
                short8v vf0 = *(const short8v*)vr;
                short8v vf1 = *(const short8v*)(vr + 32);
                short4v ub[4];
                #pragma unroll
                for (int hs = 0; hs < 4; ++hs) {
                    f32x4 u = (f32x4){0.f, 0.f, 0.f, 0.f};
                    u = __builtin_amdgcn_mfma_f32_16x16x32_bf16(vf0, ab0[hs], u, 0, 0, 0);
                    u = __builtin_amdgcn_mfma_f32_16x16x32_bf16(vf1, ab1[hs], u, 0, 0, 0);
                    #pragma unroll
                    for (int m = 0; m < 4; ++m) ub[hs][m] = f2bf(u[m]);
                }
                const short* kr = &k1lds[(loc * 16 + c) * 72 + g * 8];
                short8v af0 = *(const short8v*)kr;
                short8v af1 = *(const short8v*)(kr + 32);
                f32x4 lg = (f32x4){0.f, 0.f, 0.f, 0.f};
                lg = __builtin_amdgcn_mfma_f32_16x16x32_bf16(af0, gf0, lg, 0, 0, 0);
                lg = __builtin_amdgcn_mfma_f32_16x16x32_bf16(af1, gf1, lg, 0, 0, 0);
                int s_base = loc * 16;
                short4v eb;
                float dsum = 0.f;
                #pragma unroll
                for (int m = 0; m < 4; ++m) {
                    int s = s_base + g * 4 + m;
                    float e = (s < t && r > t) ? __expf(lg[m]) : 0.f;   // G pre-scaled 1/64
                    dsum += e;
                    eb[m] = f2bf(e);
                }
                denacc += dsum;
                #pragma unroll
                for (int hs = 0; hs < 4; ++hs)
                    numacc[hs] = __builtin_amdgcn_mfma_f32_16x16x16bf16_1k(eb, ub[hs], numacc[hs], 0, 0, 0);
            }
        }

        // epilogue for this rt
        if (__any(denacc != 0.f)) {
            float v = denacc;
            v += __shfl_xor(v, 16);
            v += __shfl_xor(v, 32);
            if (lane < 16) atomicAdd(&den[n * TT + rt * 16 + lane], v);
            #pragma unroll
            for (int hs = 0; hs < 4; ++hs)
                #pragma unroll
                for (int m = 0; m < 4; ++m)
                    atomicAdd(&num[((size_t)(n * TT + rt * 16 + g * 4 + m)) * 64 + hs * 16 + c],
                              numacc[hs][m]);
        }
    }
}

// ---------- out[t][d] = b_O[d] + (num/den)[t][:] . WOb[d][:]  (fused zdiv) -----
__global__ __launch_bounds__(512) void out_kernel(const float* __restrict__ num,
                                                  const float* __restrict__ den,
                                                  const short* __restrict__ WOb,
                                                  const float* __restrict__ bO,
                                                  float* __restrict__ out) {
    int mt = blockIdx.x & 15, dq = blockIdx.x >> 4;
    int wv = threadIdx.x >> 6, lane = threadIdx.x & 63, g = lane >> 4, c = lane & 15;
    int dt0 = dq * 16 + wv * 2;
    int t = mt * 16 + c;
    f32x4 acc[2];
    acc[0] = (f32x4){0.f, 0.f, 0.f, 0.f};
    acc[1] = (f32x4){0.f, 0.f, 0.f, 0.f};
    for (int ks = 0; ks < 16; ++ks) {
        int nh = ks * 32 + g * 8;
        int nn = nh >> 6, h = nh & 63;
        float dv = den[nn * 256 + t];
        float rcp = (dv > 0.f) ? 1.f / dv : 0.f;
        const float* np = num + ((size_t)(nn * 256 + t) * 64 + h);
        float4 f0 = *(const float4*)np;
        float4 f1 = *(const float4*)(np + 4);
        short8v a;
        a[0]=f2bf(f0.x*rcp); a[1]=f2bf(f0.y*rcp); a[2]=f2bf(f0.z*rcp); a[3]=f2bf(f0.w*rcp);
        a[4]=f2bf(f1.x*rcp); a[5]=f2bf(f1.y*rcp); a[6]=f2bf(f1.z*rcp); a[7]=f2bf(f1.w*rcp);
        #pragma unroll
        for (int u = 0; u < 2; ++u) {
            short8v b = *(const short8v*)(WOb + (size_t)((dt0 + u) * 16 + c) * 512 + ks * 32 + g * 8);
            acc[u] = __builtin_amdgcn_mfma_f32_16x16x32_bf16(a, b, acc[u], 0, 0, 0);
        }
    }
    #pragma unroll
    for (int u = 0; u < 2; ++u) {
        int d = (dt0 + u) * 16 + c;
        float bias = bO[d];
        #pragma unroll
        for (int m = 0; m < 4; ++m)
            out[(size_t)(mt * 16 + g * 4 + m) * 512 + d] = acc[u][m] + bias;
    }
}

extern "C" void kernel_launch(void* const* d_in, const int* in_sizes, int n_in,
                              void* d_out, int out_size, void* d_ws, size_t ws_size,
                              hipStream_t stream) {
    const float* x    = (const float*)d_in[0];
    const float* W_K1 = (const float*)d_in[1];
    const float* W_K2 = (const float*)d_in[2];
    const float* W_Q  = (const float*)d_in[3];
    const float* W_V1 = (const float*)d_in[4];
    const float* W_V2 = (const float*)d_in[5];
    const float* W_Kq = (const float*)d_in[6];
    const float* W_Vq = (const float*)d_in[7];
    const float* W_O  = (const float*)d_in[8];
    const float* b_K1 = (const float*)d_in[9];
    const float* b_K2 = (const float*)d_in[10];
    const float* b_Q  = (const float*)d_in[11];
    const float* b_V1 = (const float*)d_in[12];
    const float* b_V2 = (const float*)d_in[13];
    const float* b_O  = (const float*)d_in[14];
    float* ws = (float*)d_ws;
    short* sb = (short*)(ws + F_END);
    float* out = (float*)d_out;

    // all converts + num/den zeroing
    prep_kernel<<<1802, 256, 0, stream>>>(x, W_Kq, W_K1, W_K2, W_Q, W_V1, W_V2,
                                          W_Vq, W_O, sb, ws + F_NUM);

    // projections (bf16)
    proj_kernel<<<dim3(5, 8, 2), 512, 0, stream>>>(sb + S_XB, sb + S_WB,
                                                   b_K1, b_K2, b_Q, b_V1, b_V2, sb + S_PB);

    // step1[n][r][ij] and Ab[n][t][hi] in one dispatch
    bgemm_kernel<<<dim3(16, 8, 8), 256, 0, stream>>>(
        sb + S_PB + 2 * PROJ, sb + S_KQB, sb + S_S1B,
        sb + S_PB + 4 * PROJ, sb + S_VQB, sb + S_AB);

    // G in [n][t][r][i], coalesced stores, pre-scaled by 1/64
    gmat_kernel<<<512, 256, 0, stream>>>(sb + S_S1B, sb + S_PB + 1 * PROJ, sb + S_GB);

    // fused cubic attention (barrier-free, complementary-rt pairing)
    attn_kernel<<<512, 512, 0, stream>>>(sb + S_PB, sb + S_PB + 3 * PROJ,
                                         sb + S_GB, sb + S_AB,
                                         ws + F_NUM, ws + F_DEN);

    // output projection with fused zdiv
    out_kernel<<<32, 512, 0, stream>>>(ws + F_NUM, ws + F_DEN, sb + S_WOB, b_O, out);
}

// Round 16
// 136.552 us; speedup vs baseline: 1.1182x; 1.0071x over previous
//
#include <hip/hip_runtime.h>
#include <hip/hip_bf16.h>
#include <math.h>

#define TT 256   // seq len
#define DD 512   // d_model
#define NN 8     // heads
#define HH 64    // head dim
#define PROJ 131072

typedef __attribute__((ext_vector_type(8))) short short8v;   // 8 bf16
typedef __attribute__((ext_vector_type(4))) short short4v;   // 4 bf16
typedef __attribute__((ext_vector_type(4))) float f32x4;

__device__ __forceinline__ short f2bf(float x) {
    __hip_bfloat16 h = __float2bfloat16(x);   // RNE; pairs into v_cvt_pk_bf16_f32
    return *reinterpret_cast<short*>(&h);
}

#define LGKM0 asm volatile("s_waitcnt lgkmcnt(0)" ::: "memory")

// ---------------- workspace layout ----------------
// float region (floats)
#define F_NUM  0            // 131072
#define F_DEN  131072       // 2048
#define F_END  133120
// short region, base = (short*)(ws + F_END), offsets in shorts
#define S_PB   0            // 5*131072  (K1,K2,Q,V1,V2 bf16 [p][n][t][h])
#define S_XB   655360       // 131072    xb[t][d]
#define S_WB   786432       // 1310720   Wb[p][n][h][d]
#define S_KQB  2097152      // 2097152   Kqb[n][ij][k]
#define S_VQB  4194304      // 2097152   Vqb[n][h][i][j]
#define S_WOB  6291456      // 262144    WOb[d][nh]
#define S_S1B  6553600      // 8388608   S1b[n][r][ij]
#define S_AB   14942208     // 8388608   Ab[n][t][h*64+i]
#define S_GB   23330816     // 33554432  G[n][t][r][i]   (t-major, pre-scaled by 1/64)

// =============== prep: all converts + num/den zeroing in ONE dispatch =========
__global__ __launch_bounds__(256) void prep_kernel(
    const float* __restrict__ x, const float* __restrict__ W_Kq,
    const float* __restrict__ W0, const float* __restrict__ W1,
    const float* __restrict__ W2, const float* __restrict__ W3,
    const float* __restrict__ W4, const float* __restrict__ Vq,
    const float* __restrict__ WO, short* __restrict__ sb, float* __restrict__ fz)
{
    __shared__ float plds[64 * 129];
    int b = blockIdx.x;
    int tid = threadIdx.x;
    if (b < 1024) {                       // cvt W_Kq -> Kqb (natural layout)
        int i = b * 256 + tid;
        const float4 f0 = *(const float4*)(W_Kq + (size_t)i * 8);
        const float4 f1 = *(const float4*)(W_Kq + (size_t)i * 8 + 4);
        short8v o;
        o[0]=f2bf(f0.x); o[1]=f2bf(f0.y); o[2]=f2bf(f0.z); o[3]=f2bf(f0.w);
        o[4]=f2bf(f1.x); o[5]=f2bf(f1.y); o[6]=f2bf(f1.z); o[7]=f2bf(f1.w);
        *(short8v*)(sb + S_KQB + (size_t)i * 8) = o;
    } else if (b < 1088) {                // cvt x -> xb
        int i = (b - 1024) * 256 + tid;
        const float4 f0 = *(const float4*)(x + (size_t)i * 8);
        const float4 f1 = *(const float4*)(x + (size_t)i * 8 + 4);
        short8v o;
        o[0]=f2bf(f0.x); o[1]=f2bf(f0.y); o[2]=f2bf(f0.z); o[3]=f2bf(f0.w);
        o[4]=f2bf(f1.x); o[5]=f2bf(f1.y); o[6]=f2bf(f1.z); o[7]=f2bf(f1.w);
        *(short8v*)(sb + S_XB + (size_t)i * 8) = o;
    } else if (b < 1128) {                // Wb[p][n][h][d] <- W_p[n][d][h]
        int pn = b - 1088; int p = pn >> 3, n = pn & 7;
        const float* Wp = (p==0)?W0:(p==1)?W1:(p==2)?W2:(p==3)?W3:W4;
        const float* src = Wp + (size_t)n * DD * HH;
        short* dst = sb + S_WB + (size_t)pn * HH * DD;
        for (int d0 = 0; d0 < DD; d0 += 64) {
            __syncthreads();
            for (int it = 0; it < 16; ++it) {
                int m = it * 256 + tid;
                int dl = m >> 6, h = m & 63;
                plds[h * 65 + dl] = src[(size_t)(d0 + dl) * 64 + h];
            }
            __syncthreads();
            int h = tid >> 2, seg = tid & 3;
            short8v o0, o1;
            #pragma unroll
            for (int e = 0; e < 8; ++e) o0[e] = f2bf(plds[h * 65 + seg * 16 + e]);
            #pragma unroll
            for (int e = 0; e < 8; ++e) o1[e] = f2bf(plds[h * 65 + seg * 16 + 8 + e]);
            *(short8v*)(dst + (size_t)h * DD + d0 + seg * 16) = o0;
            *(short8v*)(dst + (size_t)h * DD + d0 + seg * 16 + 8) = o1;
        }
    } else if (b < 1640) {                // Vqb[n][h][i][j] <- W_Vq[n][i][j][h]
        int bb = b - 1128; int n = bb >> 6, i = bb & 63;
        const float* src = Vq + (size_t)(n * 64 + i) * 4096;
        for (int it = 0; it < 16; ++it) {
            int m = it * 256 + tid;
            int j = m >> 6, h = m & 63;
            plds[h * 65 + j] = src[(size_t)j * 64 + h];
        }
        __syncthreads();
        int h = tid >> 2, seg = tid & 3;
        short8v o0, o1;
        #pragma unroll
        for (int e = 0; e < 8; ++e) o0[e] = f2bf(plds[h * 65 + seg * 16 + e]);
        #pragma unroll
        for (int e = 0; e < 8; ++e) o1[e] = f2bf(plds[h * 65 + seg * 16 + 8 + e]);
        short* dst = sb + S_VQB + (size_t)n * 262144 + (size_t)h * 4096 + i * 64 + seg * 16;
        *(short8v*)dst = o0;
        *(short8v*)(dst + 8) = o1;
    } else if (b < 1672) {                // WOb[d][nh] <- W_O[nh][d]
        int bb = b - 1640; int dc = bb & 7, nhc = bb >> 3;
        for (int it = 0; it < 32; ++it) {
            int m = it * 256 + tid;
            int nhl = m >> 6, dl = m & 63;
            plds[dl * 129 + nhl] = WO[(size_t)(nhc * 128 + nhl) * 512 + dc * 64 + dl];
        }
        __syncthreads();
        for (int it = 0; it < 4; ++it) {
            int m = it * 256 + tid;
            int dl = m >> 4, seg = m & 15;
            short8v o;
            #pragma unroll
            for (int e = 0; e < 8; ++e) o[e] = f2bf(plds[dl * 129 + seg * 8 + e]);
            *(short8v*)(sb + S_WOB + (size_t)(dc * 64 + dl) * 512 + nhc * 128 + seg * 8) = o;
        }
    } else {                              // zero num+den (130 blocks x 1024 floats)
        int i = (b - 1672) * 1024 + tid * 4;
        *(float4*)(fz + i) = make_float4(0.f, 0.f, 0.f, 0.f);
    }
}

// ---------------- proj (MFMA): Pb[p][n][t][h] = xb[t][:] . Wb[p][n][h][:] + b --
// grid (5, 8, 4), 256 threads: 160 blocks for better CU coverage.
__global__ __launch_bounds__(256) void proj_kernel(
    const short* __restrict__ xb, const short* __restrict__ Wb,
    const float* __restrict__ bK1, const float* __restrict__ bK2,
    const float* __restrict__ bQ,  const float* __restrict__ bV1,
    const float* __restrict__ bV2, short* __restrict__ Pb) {
    int p = blockIdx.x, n = blockIdx.y, q = blockIdx.z;
    int wv = threadIdx.x >> 6, lane = threadIdx.x & 63, g = lane >> 4, c = lane & 15;
    __shared__ short wlds[64 * 520];
    __shared__ short sbuf[4][16 * 72];
    const short* wsrc = Wb + (size_t)(p * 8 + n) * HH * DD;
    for (int it = 0; it < 16; ++it) {
        int idx = it * 256 + threadIdx.x;
        int h = idx >> 6, seg = idx & 63;
        *(short8v*)(&wlds[h * 520 + seg * 8]) = *(const short8v*)(wsrc + (size_t)h * DD + seg * 8);
    }
    __syncthreads();
    int mt = q * 4 + wv;
    f32x4 acc[4];
    #pragma unroll
    for (int ct = 0; ct < 4; ++ct) acc[ct] = (f32x4){0.f, 0.f, 0.f, 0.f};
    for (int ks = 0; ks < 16; ++ks) {
        short8v a = *(const short8v*)(xb + (size_t)(mt * 16 + c) * DD + ks * 32 + g * 8);
        #pragma unroll
        for (int ct = 0; ct < 4; ++ct) {
            short8v b = *(const short8v*)(&wlds[(ct * 16 + c) * 520 + ks * 32 + g * 8]);
            acc[ct] = __builtin_amdgcn_mfma_f32_16x16x32_bf16(a, b, acc[ct], 0, 0, 0);
        }
    }
    const float* bp = (p == 0) ? bK1 : (p == 1) ? bK2 : (p == 2) ? bQ : (p == 3) ? bV1 : bV2;
    short* sbw = &sbuf[wv][0];
    #pragma unroll
    for (int ct = 0; ct < 4; ++ct) {
        float bias = bp[n * 64 + ct * 16 + c];
        #pragma unroll
        for (int m = 0; m < 4; ++m)
            sbw[(g * 4 + m) * 72 + ct * 16 + c] = f2bf(acc[ct][m] + bias);
    }
    LGKM0;
    int rl = lane & 15, sg = lane >> 4;
    short8v o0 = *(const short8v*)(&sbw[rl * 72 + sg * 16]);
    short8v o1 = *(const short8v*)(&sbw[rl * 72 + sg * 16 + 8]);
    short* dst = Pb + (size_t)p * PROJ + (size_t)(n * 256 + mt * 16 + rl) * 64 + sg * 16;
    *(short8v*)dst = o0;
    *(short8v*)(dst + 8) = o1;
}

// ------ merged batch GEMM: z<4 -> step1 (A0,B0,O0), z>=4 -> Ab (A1,B1,O1) ------
__global__ __launch_bounds__(256) void bgemm_kernel(
    const short* __restrict__ A0, const short* __restrict__ B0, short* __restrict__ O0,
    const short* __restrict__ A1, const short* __restrict__ B1, short* __restrict__ O1) {
    int mt = blockIdx.x, n = blockIdx.y, z = blockIdx.z;
    const short* A = (z < 4) ? A0 : A1;
    const short* B = (z < 4) ? B0 : B1;
    short* out = (z < 4) ? O0 : O1;
    int cgq = z & 3;
    int wv = threadIdx.x >> 6, lane = threadIdx.x & 63, g = lane >> 4, c = lane & 15;
    __shared__ short sbuf[4][16 * 72];
    short* sbw = &sbuf[wv][0];
    const short* abase = A + ((size_t)n * 256 + mt * 16 + c) * 64 + g * 8;
    short8v a0 = *(const short8v*)abase;
    short8v a1 = *(const short8v*)(abase + 32);
    for (int cg = cgq * 16 + wv; cg < cgq * 16 + 16; cg += 4) {
        f32x4 acc[4];
        #pragma unroll
        for (int jt = 0; jt < 4; ++jt) acc[jt] = (f32x4){0.f, 0.f, 0.f, 0.f};
        const short* bb = B + ((size_t)n * 4096 + cg * 64) * 64;
        #pragma unroll
        for (int jt = 0; jt < 4; ++jt) {
            short8v b0 = *(const short8v*)(bb + (size_t)(jt * 16 + c) * 64 + g * 8);
            short8v b1 = *(const short8v*)(bb + (size_t)(jt * 16 + c) * 64 + g * 8 + 32);
            acc[jt] = __builtin_amdgcn_mfma_f32_16x16x32_bf16(a0, b0, acc[jt], 0, 0, 0);
            acc[jt] = __builtin_amdgcn_mfma_f32_16x16x32_bf16(a1, b1, acc[jt], 0, 0, 0);
        }
        LGKM0;
        #pragma unroll
        for (int jt = 0; jt < 4; ++jt)
            #pragma unroll
            for (int m = 0; m < 4; ++m)
                sbw[(g * 4 + m) * 72 + jt * 16 + c] = f2bf(acc[jt][m]);
        LGKM0;
        int rl = lane & 15, sg = lane >> 4;
        short8v o0 = *(const short8v*)(&sbw[rl * 72 + sg * 16]);
        short8v o1 = *(const short8v*)(&sbw[rl * 72 + sg * 16 + 8]);
        short* dst = out + ((size_t)n * 256 + mt * 16 + rl) * 4096 + cg * 64 + sg * 16;
        *(short8v*)dst = o0;
        *(short8v*)(dst + 8) = o1;
    }
}

// ---------- G[n][t][r][i] = (1/64) sum_j S1[n][r][i][j]*k2[n][t][j] ------------
__global__ __launch_bounds__(256) void gmat_kernel(const short* __restrict__ S1b,
                                                   const short* __restrict__ K2b,
                                                   short* __restrict__ G) {
    int bid = blockIdx.x;
    int n = bid & 7;
    int tt = (bid >> 3) & 15;
    int rq = bid >> 7;
    int wv = threadIdx.x >> 6, lane = threadIdx.x & 63, g = lane >> 4, c = lane & 15;
    int t0 = tt * 16;
    __shared__ short sbuf[4][16 * 68];
    short* sbw = &sbuf[wv][0];
    const short* abase = K2b + ((size_t)n * TT + t0 + c) * 64 + g * 8;
    short8v a0 = *(const short8v*)abase;
    short8v a1 = *(const short8v*)(abase + 32);
    for (int r = t0 + rq * 4 + wv; r < 256; r += 16) {
        const short* bb = S1b + ((size_t)(n * 256 + r) * 64) * 64;
        f32x4 acc[4];
        #pragma unroll
        for (int it = 0; it < 4; ++it) {
            short8v b0 = *(const short8v*)(bb + (size_t)(it * 16 + c) * 64 + g * 8);
            short8v b1 = *(const short8v*)(bb + (size_t)(it * 16 + c) * 64 + g * 8 + 32);
            acc[it] = (f32x4){0.f, 0.f, 0.f, 0.f};
            acc[it] = __builtin_amdgcn_mfma_f32_16x16x32_bf16(a0, b0, acc[it], 0, 0, 0);
            acc[it] = __builtin_amdgcn_mfma_f32_16x16x32_bf16(a1, b1, acc[it], 0, 0, 0);
        }
        LGKM0;   // previous iteration's sbuf reads complete
        #pragma unroll
        for (int it = 0; it < 4; ++it)
            #pragma unroll
            for (int m = 0; m < 4; ++m)
                sbw[(g * 4 + m) * 68 + it * 16 + c] = f2bf(acc[it][m] * 0.015625f);
        LGKM0;
        int trow = lane >> 2, seg = (lane & 3) * 16;
        short8v o0 = *(const short8v*)(&sbw[trow * 68 + seg]);
        short8v o1 = *(const short8v*)(&sbw[trow * 68 + seg + 8]);
        short* dst = G + (((size_t)(n * TT + t0 + trow)) * TT + r) * 64 + seg;
        *(short8v*)dst = o0;
        *(short8v*)(dst + 8) = o1;
    }
}

// ---------- fused cubic attention: barrier-free, rt-paired, Ab-prefetched -----
// grid 512: n=bid&7 (XCD affinity), rtpair=(bid>>3)&7, tq=bid>>6 (0..7).
// Block handles rt_a=rtpair AND rt_b=15-rtpair sequentially (uniform work).
// 8 waves; wave wv handles t in {tq+8wv+64k}. U tiles in-register; the Ab
// fragments for the NEXT t are loaded during the current t's consume (valid
// waves only -> no speculative traffic).
__global__ __launch_bounds__(512) void attn_kernel(
    const short* __restrict__ K1b, const short* __restrict__ V1b,
    const short* __restrict__ Gm, const short* __restrict__ Ab,
    float* __restrict__ num, float* __restrict__ den)
{
    int bid = blockIdx.x;
    int n = bid & 7;
    int rt_a = (bid >> 3) & 7;
    int rt_b = 15 - rt_a;
    int tq = bid >> 6;            // 0..7
    int tid = threadIdx.x;
    int wv = tid >> 6, lane = tid & 63, g = lane >> 4, c = lane & 15;

    __shared__ short k1lds[256 * 72];   // 36.9 KB
    __shared__ short v1lds[256 * 72];   // 36.9 KB

    int rows = (rt_b + 1) * 16;         // rt_b >= rt_a; covers both phases
    if (rows > 256) rows = 256;

    for (int idx = tid; idx < rows * 8; idx += 512) {
        int row = idx >> 3, seg = idx & 7;
        *(short8v*)(&k1lds[row * 72 + seg * 8]) =
            *(const short8v*)(K1b + ((size_t)n * TT + row) * 64 + seg * 8);
        *(short8v*)(&v1lds[row * 72 + seg * 8]) =
            *(const short8v*)(V1b + ((size_t)n * TT + row) * 64 + seg * 8);
    }
    __syncthreads();   // the only barrier

    #pragma unroll
    for (int phase = 0; phase < 2; ++phase) {
        int rt = phase ? rt_b : rt_a;
        int tmax = rt * 16 + 14;
        if (tmax > 254) tmax = 254;
        int r = rt * 16 + c;

        f32x4 numacc[4];
        #pragma unroll
        for (int b = 0; b < 4; ++b) numacc[b] = (f32x4){0.f, 0.f, 0.f, 0.f};
        float denacc = 0.f;

        int tfirst = tq + 8 * wv;

        // prologue: prefetch Ab for the first t this wave will process
        short8v abN0_0, abN0_1, abN0_2, abN0_3, abN1_0, abN1_1, abN1_2, abN1_3;
        if (tfirst <= tmax) {
            const short* ar = Ab + (size_t)(n * TT + tfirst) * 4096 + c * 64 + g * 8;
            abN0_0 = *(const short8v*)(ar);            abN1_0 = *(const short8v*)(ar + 32);
            abN0_1 = *(const short8v*)(ar + 1024);     abN1_1 = *(const short8v*)(ar + 1056);
            abN0_2 = *(const short8v*)(ar + 2048);     abN1_2 = *(const short8v*)(ar + 2080);
            abN0_3 = *(const short8v*)(ar + 3072);     abN1_3 = *(const short8v*)(ar + 3104);
        }

        for (int t = tfirst; t <= tmax; t += 64) {
            short8v ab0[4], ab1[4];
            ab0[0] = abN0_0; ab0[1] = abN0_1; ab0[2] = abN0_2; ab0[3] = abN0_3;
            ab1[0] = abN1_0; ab1[1] = abN1_1; ab1[2] = abN1_2; ab1[3] = abN1_3;
            // prefetch Ab for t+64 (covered by this t's entire consume)
            if (t + 64 <= tmax) {
                const short* ar = Ab + (size_t)(n * TT + t + 64) * 4096 + c * 64 + g * 8;
                abN0_0 = *(const short8v*)(ar);            abN1_0 = *(const short8v*)(ar + 32);
                abN0_1 = *(const short8v*)(ar + 1024);     abN1_1 = *(const short8v*)(ar + 1056);
                abN0_2 = *(const short8v*)(ar + 2048);     abN1_2 = *(const short8v*)(ar + 2080);
                abN0_3 = *(const short8v*)(ar + 3072);     abN1_3 = *(const short8v*)(ar + 3104);
            }
            if (t < 1) continue;
            int cntU = ((t - 1) >> 4) + 1;  // 1..16 s-tiles

            const short* gb = Gm + (((size_t)(n * TT + t) * TT) + rt * 16 + c) * 64 + g * 8;
            short8v gf0 = *(const short8v*)gb;
            short8v gf1 = *(const short8v*)(gb + 32);

            for (int loc = 0; loc < cntU; ++loc) {
                const short* vr = &v1lds[(loc * 16 + c) * 72 + g * 8];
                short8v vf0 = *(const short8v*)vr;
                short8v vf1 = *(const short8v*)(vr + 32);
                short4v ub[4];
                #pragma unroll
                for (int hs = 0; hs < 4; ++hs) {
                    f32x4 u = (f32x4){0.f, 0.f, 0.f, 0.f};
                    u = __builtin_amdgcn_mfma_f32_16x16x32_bf16(vf0, ab0[hs], u, 0, 0, 0);
                    u = __builtin_amdgcn_mfma_f32_16x16x32_bf16(vf1, ab1[hs], u, 0, 0, 0);
                    #pragma unroll
                    for (int m = 0; m < 4; ++m) ub[hs][m] = f2bf(u[m]);
                }
                const short* kr = &k1lds[(loc * 16 + c) * 72 + g * 8];
                short8v af0 = *(const short8v*)kr;
                short8v af1 = *(const short8v*)(kr + 32);
                f32x4 lg = (f32x4){0.f, 0.f, 0.f, 0.f};
                lg = __builtin_amdgcn_mfma_f32_16x16x32_bf16(af0, gf0, lg, 0, 0, 0);
                lg = __builtin_amdgcn_mfma_f32_16x16x32_bf16(af1, gf1, lg, 0, 0, 0);
                int s_base = loc * 16;
                short4v eb;
                float dsum = 0.f;
                #pragma unroll
                for (int m = 0; m < 4; ++m) {
                    int s = s_base + g * 4 + m;
                    float e = (s < t && r > t) ? __expf(lg[m]) : 0.f;   // G pre-scaled 1/64
                    dsum += e;
                    eb[m] = f2bf(e);
                }
                denacc += dsum;
                #pragma unroll
                for (int hs = 0; hs < 4; ++hs)
                    numacc[hs] = __builtin_amdgcn_mfma_f32_16x16x16bf16_1k(eb, ub[hs], numacc[hs], 0, 0, 0);
            }
        }

        // epilogue for this rt
        if (__any(denacc != 0.f)) {
            float v = denacc;
            v += __shfl_xor(v, 16);
            v += __shfl_xor(v, 32);
            if (lane < 16) atomicAdd(&den[n * TT + rt * 16 + lane], v);
            #pragma unroll
            for (int hs = 0; hs < 4; ++hs)
                #pragma unroll
                for (int m = 0; m < 4; ++m)
                    atomicAdd(&num[((size_t)(n * TT + rt * 16 + g * 4 + m)) * 64 + hs * 16 + c],
                              numacc[hs][m]);
        }
    }
}

// ---------- out[t][d] = b_O[d] + (num/den)[t][:] . WOb[d][:]  (fused zdiv) -----
// grid 64: mt=bid&15, dq=bid>>4 (0..3); each wave owns one d-tile.
__global__ __launch_bounds__(512) void out_kernel(const float* __restrict__ num,
                                                  const float* __restrict__ den,
                                                  const short* __restrict__ WOb,
                                                  const float* __restrict__ bO,
                                                  float* __restrict__ out) {
    int mt = blockIdx.x & 15, dq = blockIdx.x >> 4;
    int wv = threadIdx.x >> 6, lane = threadIdx.x & 63, g = lane >> 4, c = lane & 15;
    int dt = dq * 8 + wv;     // 0..31
    int t = mt * 16 + c;
    f32x4 acc = (f32x4){0.f, 0.f, 0.f, 0.f};
    for (int ks = 0; ks < 16; ++ks) {
        int nh = ks * 32 + g * 8;
        int nn = nh >> 6, h = nh & 63;
        float dv = den[nn * 256 + t];
        float rcp = (dv > 0.f) ? 1.f / dv : 0.f;
        const float* np = num + ((size_t)(nn * 256 + t) * 64 + h);
        float4 f0 = *(const float4*)np;
        float4 f1 = *(const float4*)(np + 4);
        short8v a;
        a[0]=f2bf(f0.x*rcp); a[1]=f2bf(f0.y*rcp); a[2]=f2bf(f0.z*rcp); a[3]=f2bf(f0.w*rcp);
        a[4]=f2bf(f1.x*rcp); a[5]=f2bf(f1.y*rcp); a[6]=f2bf(f1.z*rcp); a[7]=f2bf(f1.w*rcp);
        short8v b = *(const short8v*)(WOb + (size_t)(dt * 16 + c) * 512 + ks * 32 + g * 8);
        acc = __builtin_amdgcn_mfma_f32_16x16x32_bf16(a, b, acc, 0, 0, 0);
    }
    int d = dt * 16 + c;
    float bias = bO[d];
    #pragma unroll
    for (int m = 0; m < 4; ++m)
        out[(size_t)(mt * 16 + g * 4 + m) * 512 + d] = acc[m] + bias;
}

extern "C" void kernel_launch(void* const* d_in, const int* in_sizes, int n_in,
                              void* d_out, int out_size, void* d_ws, size_t ws_size,
                              hipStream_t stream) {
    const float* x    = (const float*)d_in[0];
    const float* W_K1 = (const float*)d_in[1];
    const float* W_K2 = (const float*)d_in[2];
    const float* W_Q  = (const float*)d_in[3];
    const float* W_V1 = (const float*)d_in[4];
    const float* W_V2 = (const float*)d_in[5];
    const float* W_Kq = (const float*)d_in[6];
    const float* W_Vq = (const float*)d_in[7];
    const float* W_O  = (const float*)d_in[8];
    const float* b_K1 = (const float*)d_in[9];
    const float* b_K2 = (const float*)d_in[10];
    const float* b_Q  = (const float*)d_in[11];
    const float* b_V1 = (const float*)d_in[12];
    const float* b_V2 = (const float*)d_in[13];
    const float* b_O  = (const float*)d_in[14];
    float* ws = (float*)d_ws;
    short* sb = (short*)(ws + F_END);
    float* out = (float*)d_out;

    // all converts + num/den zeroing
    prep_kernel<<<1802, 256, 0, stream>>>(x, W_Kq, W_K1, W_K2, W_Q, W_V1, W_V2,
                                          W_Vq, W_O, sb, ws + F_NUM);

    // projections (bf16), 160 blocks
    proj_kernel<<<dim3(5, 8, 4), 256, 0, stream>>>(sb + S_XB, sb + S_WB,
                                                   b_K1, b_K2, b_Q, b_V1, b_V2, sb + S_PB);

    // step1[n][r][ij] and Ab[n][t][hi] in one dispatch
    bgemm_kernel<<<dim3(16, 8, 8), 256, 0, stream>>>(
        sb + S_PB + 2 * PROJ, sb + S_KQB, sb + S_S1B,
        sb + S_PB + 4 * PROJ, sb + S_VQB, sb + S_AB);

    // G in [n][t][r][i], coalesced stores, pre-scaled by 1/64
    gmat_kernel<<<512, 256, 0, stream>>>(sb + S_S1B, sb + S_PB + 1 * PROJ, sb + S_GB);

    // fused cubic attention (barrier-free, rt-paired, Ab-prefetched)
    attn_kernel<<<512, 512, 0, stream>>>(sb + S_PB, sb + S_PB + 3 * PROJ,
                                         sb + S_GB, sb + S_AB,
                                         ws + F_NUM, ws + F_DEN);

    // output projection with fused zdiv, 64 blocks
    out_kernel<<<64, 512, 0, stream>>>(ws + F_NUM, ws + F_DEN, sb + S_WOB, b_O, out);
}

// Round 17
// 132.946 us; speedup vs baseline: 1.1486x; 1.0271x over previous
//
#include <hip/hip_runtime.h>
#include <hip/hip_bf16.h>
#include <math.h>

#define TT 256   // seq len
#define DD 512   // d_model
#define NN 8     // heads
#define HH 64    // head dim
#define PROJ 131072

typedef __attribute__((ext_vector_type(8))) short short8v;   // 8 bf16
typedef __attribute__((ext_vector_type(4))) short short4v;   // 4 bf16
typedef __attribute__((ext_vector_type(4))) float f32x4;

__device__ __forceinline__ short f2bf(float x) {
    __hip_bfloat16 h = __float2bfloat16(x);   // RNE; pairs into v_cvt_pk_bf16_f32
    return *reinterpret_cast<short*>(&h);
}

#define LGKM0 asm volatile("s_waitcnt lgkmcnt(0)" ::: "memory")

// ---------------- workspace layout ----------------
// float region (floats)
#define F_NUM  0            // 131072
#define F_DEN  131072       // 2048
#define F_END  133120
// short region, base = (short*)(ws + F_END), offsets in shorts
#define S_PB   0            // 5*131072  (K1,K2,Q,V1,V2 bf16 [p][n][t][h])
#define S_XB   655360       // 131072    xb[t][d]
#define S_WB   786432       // 1310720   Wb[p][n][h][d]
#define S_KQB  2097152      // 2097152   Kqb[n][ij][k]
#define S_VQB  4194304      // 2097152   Vqb[n][h][i][j]
#define S_WOB  6291456      // 262144    WOb[d][nh]
#define S_S1B  6553600      // 8388608   S1b[n][r][ij]
#define S_AB   14942208     // 8388608   Ab[n][t][h*64+i]
#define S_GB   23330816     // 33554432  G[n][t][r][i]   (t-major, pre-scaled by 1/64)

// =============== prep: all converts + num/den zeroing in ONE dispatch =========
__global__ __launch_bounds__(256) void prep_kernel(
    const float* __restrict__ x, const float* __restrict__ W_Kq,
    const float* __restrict__ W0, const float* __restrict__ W1,
    const float* __restrict__ W2, const float* __restrict__ W3,
    const float* __restrict__ W4, const float* __restrict__ Vq,
    const float* __restrict__ WO, short* __restrict__ sb, float* __restrict__ fz)
{
    __shared__ float plds[64 * 129];
    int b = blockIdx.x;
    int tid = threadIdx.x;
    if (b < 1024) {                       // cvt W_Kq -> Kqb (natural layout)
        int i = b * 256 + tid;
        const float4 f0 = *(const float4*)(W_Kq + (size_t)i * 8);
        const float4 f1 = *(const float4*)(W_Kq + (size_t)i * 8 + 4);
        short8v o;
        o[0]=f2bf(f0.x); o[1]=f2bf(f0.y); o[2]=f2bf(f0.z); o[3]=f2bf(f0.w);
        o[4]=f2bf(f1.x); o[5]=f2bf(f1.y); o[6]=f2bf(f1.z); o[7]=f2bf(f1.w);
        *(short8v*)(sb + S_KQB + (size_t)i * 8) = o;
    } else if (b < 1088) {                // cvt x -> xb
        int i = (b - 1024) * 256 + tid;
        const float4 f0 = *(const float4*)(x + (size_t)i * 8);
        const float4 f1 = *(const float4*)(x + (size_t)i * 8 + 4);
        short8v o;
        o[0]=f2bf(f0.x); o[1]=f2bf(f0.y); o[2]=f2bf(f0.z); o[3]=f2bf(f0.w);
        o[4]=f2bf(f1.x); o[5]=f2bf(f1.y); o[6]=f2bf(f1.z); o[7]=f2bf(f1.w);
        *(short8v*)(sb + S_XB + (size_t)i * 8) = o;
    } else if (b < 1128) {                // Wb[p][n][h][d] <- W_p[n][d][h]
        int pn = b - 1088; int p = pn >> 3, n = pn & 7;
        const float* Wp = (p==0)?W0:(p==1)?W1:(p==2)?W2:(p==3)?W3:W4;
        const float* src = Wp + (size_t)n * DD * HH;
        short* dst = sb + S_WB + (size_t)pn * HH * DD;
        for (int d0 = 0; d0 < DD; d0 += 64) {
            __syncthreads();
            for (int it = 0; it < 16; ++it) {
                int m = it * 256 + tid;
                int dl = m >> 6, h = m & 63;
                plds[h * 65 + dl] = src[(size_t)(d0 + dl) * 64 + h];
            }
            __syncthreads();
            int h = tid >> 2, seg = tid & 3;
            short8v o0, o1;
            #pragma unroll
            for (int e = 0; e < 8; ++e) o0[e] = f2bf(plds[h * 65 + seg * 16 + e]);
            #pragma unroll
            for (int e = 0; e < 8; ++e) o1[e] = f2bf(plds[h * 65 + seg * 16 + 8 + e]);
            *(short8v*)(dst + (size_t)h * DD + d0 + seg * 16) = o0;
            *(short8v*)(dst + (size_t)h * DD + d0 + seg * 16 + 8) = o1;
        }
    } else if (b < 1640) {                // Vqb[n][h][i][j] <- W_Vq[n][i][j][h]
        int bb = b - 1128; int n = bb >> 6, i = bb & 63;
        const float* src = Vq + (size_t)(n * 64 + i) * 4096;
        for (int it = 0; it < 16; ++it) {
            int m = it * 256 + tid;
            int j = m >> 6, h = m & 63;
            plds[h * 65 + j] = src[(size_t)j * 64 + h];
        }
        __syncthreads();
        int h = tid >> 2, seg = tid & 3;
        short8v o0, o1;
        #pragma unroll
        for (int e = 0; e < 8; ++e) o0[e] = f2bf(plds[h * 65 + seg * 16 + e]);
        #pragma unroll
        for (int e = 0; e < 8; ++e) o1[e] = f2bf(plds[h * 65 + seg * 16 + 8 + e]);
        short* dst = sb + S_VQB + (size_t)n * 262144 + (size_t)h * 4096 + i * 64 + seg * 16;
        *(short8v*)dst = o0;
        *(short8v*)(dst + 8) = o1;
    } else if (b < 1672) {                // WOb[d][nh] <- W_O[nh][d]
        int bb = b - 1640; int dc = bb & 7, nhc = bb >> 3;
        for (int it = 0; it < 32; ++it) {
            int m = it * 256 + tid;
            int nhl = m >> 6, dl = m & 63;
            plds[dl * 129 + nhl] = WO[(size_t)(nhc * 128 + nhl) * 512 + dc * 64 + dl];
        }
        __syncthreads();
        for (int it = 0; it < 4; ++it) {
            int m = it * 256 + tid;
            int dl = m >> 4, seg = m & 15;
            short8v o;
            #pragma unroll
            for (int e = 0; e < 8; ++e) o[e] = f2bf(plds[dl * 129 + seg * 8 + e]);
            *(short8v*)(sb + S_WOB + (size_t)(dc * 64 + dl) * 512 + nhc * 128 + seg * 8) = o;
        }
    } else {                              // zero num+den (130 blocks x 1024 floats)
        int i = (b - 1672) * 1024 + tid * 4;
        *(float4*)(fz + i) = make_float4(0.f, 0.f, 0.f, 0.f);
    }
}

// ---------------- proj (MFMA): Pb[p][n][t][h] = xb[t][:] . Wb[p][n][h][:] + b --
// grid (5, 8, 4), 256 threads: 160 blocks for better CU coverage.
__global__ __launch_bounds__(256) void proj_kernel(
    const short* __restrict__ xb, const short* __restrict__ Wb,
    const float* __restrict__ bK1, const float* __restrict__ bK2,
    const float* __restrict__ bQ,  const float* __restrict__ bV1,
    const float* __restrict__ bV2, short* __restrict__ Pb) {
    int p = blockIdx.x, n = blockIdx.y, q = blockIdx.z;
    int wv = threadIdx.x >> 6, lane = threadIdx.x & 63, g = lane >> 4, c = lane & 15;
    __shared__ short wlds[64 * 520];
    __shared__ short sbuf[4][16 * 72];
    const short* wsrc = Wb + (size_t)(p * 8 + n) * HH * DD;
    for (int it = 0; it < 16; ++it) {
        int idx = it * 256 + threadIdx.x;
        int h = idx >> 6, seg = idx & 63;
        *(short8v*)(&wlds[h * 520 + seg * 8]) = *(const short8v*)(wsrc + (size_t)h * DD + seg * 8);
    }
    __syncthreads();
    int mt = q * 4 + wv;
    f32x4 acc[4];
    #pragma unroll
    for (int ct = 0; ct < 4; ++ct) acc[ct] = (f32x4){0.f, 0.f, 0.f, 0.f};
    for (int ks = 0; ks < 16; ++ks) {
        short8v a = *(const short8v*)(xb + (size_t)(mt * 16 + c) * DD + ks * 32 + g * 8);
        #pragma unroll
        for (int ct = 0; ct < 4; ++ct) {
            short8v b = *(const short8v*)(&wlds[(ct * 16 + c) * 520 + ks * 32 + g * 8]);
            acc[ct] = __builtin_amdgcn_mfma_f32_16x16x32_bf16(a, b, acc[ct], 0, 0, 0);
        }
    }
    const float* bp = (p == 0) ? bK1 : (p == 1) ? bK2 : (p == 2) ? bQ : (p == 3) ? bV1 : bV2;
    short* sbw = &sbuf[wv][0];
    #pragma unroll
    for (int ct = 0; ct < 4; ++ct) {
        float bias = bp[n * 64 + ct * 16 + c];
        #pragma unroll
        for (int m = 0; m < 4; ++m)
            sbw[(g * 4 + m) * 72 + ct * 16 + c] = f2bf(acc[ct][m] + bias);
    }
    LGKM0;
    int rl = lane & 15, sg = lane >> 4;
    short8v o0 = *(const short8v*)(&sbw[rl * 72 + sg * 16]);
    short8v o1 = *(const short8v*)(&sbw[rl * 72 + sg * 16 + 8]);
    short* dst = Pb + (size_t)p * PROJ + (size_t)(n * 256 + mt * 16 + rl) * 64 + sg * 16;
    *(short8v*)dst = o0;
    *(short8v*)(dst + 8) = o1;
}

// ------ merged batch GEMM: z<4 -> step1 (A0,B0,O0), z>=4 -> Ab (A1,B1,O1) ------
__global__ __launch_bounds__(256) void bgemm_kernel(
    const short* __restrict__ A0, const short* __restrict__ B0, short* __restrict__ O0,
    const short* __restrict__ A1, const short* __restrict__ B1, short* __restrict__ O1) {
    int mt = blockIdx.x, n = blockIdx.y, z = blockIdx.z;
    const short* A = (z < 4) ? A0 : A1;
    const short* B = (z < 4) ? B0 : B1;
    short* out = (z < 4) ? O0 : O1;
    int cgq = z & 3;
    int wv = threadIdx.x >> 6, lane = threadIdx.x & 63, g = lane >> 4, c = lane & 15;
    __shared__ short sbuf[4][16 * 72];
    short* sbw = &sbuf[wv][0];
    const short* abase = A + ((size_t)n * 256 + mt * 16 + c) * 64 + g * 8;
    short8v a0 = *(const short8v*)abase;
    short8v a1 = *(const short8v*)(abase + 32);
    for (int cg = cgq * 16 + wv; cg < cgq * 16 + 16; cg += 4) {
        f32x4 acc[4];
        #pragma unroll
        for (int jt = 0; jt < 4; ++jt) acc[jt] = (f32x4){0.f, 0.f, 0.f, 0.f};
        const short* bb = B + ((size_t)n * 4096 + cg * 64) * 64;
        #pragma unroll
        for (int jt = 0; jt < 4; ++jt) {
            short8v b0 = *(const short8v*)(bb + (size_t)(jt * 16 + c) * 64 + g * 8);
            short8v b1 = *(const short8v*)(bb + (size_t)(jt * 16 + c) * 64 + g * 8 + 32);
            acc[jt] = __builtin_amdgcn_mfma_f32_16x16x32_bf16(a0, b0, acc[jt], 0, 0, 0);
            acc[jt] = __builtin_amdgcn_mfma_f32_16x16x32_bf16(a1, b1, acc[jt], 0, 0, 0);
        }
        LGKM0;
        #pragma unroll
        for (int jt = 0; jt < 4; ++jt)
            #pragma unroll
            for (int m = 0; m < 4; ++m)
                sbw[(g * 4 + m) * 72 + jt * 16 + c] = f2bf(acc[jt][m]);
        LGKM0;
        int rl = lane & 15, sg = lane >> 4;
        short8v o0 = *(const short8v*)(&sbw[rl * 72 + sg * 16]);
        short8v o1 = *(const short8v*)(&sbw[rl * 72 + sg * 16 + 8]);
        short* dst = out + ((size_t)n * 256 + mt * 16 + rl) * 4096 + cg * 64 + sg * 16;
        *(short8v*)dst = o0;
        *(short8v*)(dst + 8) = o1;
    }
}

// ---------- G[n][t][r][i] = (1/64) sum_j S1[n][r][i][j]*k2[n][t][j] ------------
__global__ __launch_bounds__(256) void gmat_kernel(const short* __restrict__ S1b,
                                                   const short* __restrict__ K2b,
                                                   short* __restrict__ G) {
    int bid = blockIdx.x;
    int n = bid & 7;
    int tt = (bid >> 3) & 15;
    int rq = bid >> 7;
    int wv = threadIdx.x >> 6, lane = threadIdx.x & 63, g = lane >> 4, c = lane & 15;
    int t0 = tt * 16;
    __shared__ short sbuf[4][16 * 68];
    short* sbw = &sbuf[wv][0];
    const short* abase = K2b + ((size_t)n * TT + t0 + c) * 64 + g * 8;
    short8v a0 = *(const short8v*)abase;
    short8v a1 = *(const short8v*)(abase + 32);
    for (int r = t0 + rq * 4 + wv; r < 256; r += 16) {
        const short* bb = S1b + ((size_t)(n * 256 + r) * 64) * 64;
        f32x4 acc[4];
        #pragma unroll
        for (int it = 0; it < 4; ++it) {
            short8v b0 = *(const short8v*)(bb + (size_t)(it * 16 + c) * 64 + g * 8);
            short8v b1 = *(const short8v*)(bb + (size_t)(it * 16 + c) * 64 + g * 8 + 32);
            acc[it] = (f32x4){0.f, 0.f, 0.f, 0.f};
            acc[it] = __builtin_amdgcn_mfma_f32_16x16x32_bf16(a0, b0, acc[it], 0, 0, 0);
            acc[it] = __builtin_amdgcn_mfma_f32_16x16x32_bf16(a1, b1, acc[it], 0, 0, 0);
        }
        LGKM0;   // previous iteration's sbuf reads complete
        #pragma unroll
        for (int it = 0; it < 4; ++it)
            #pragma unroll
            for (int m = 0; m < 4; ++m)
                sbw[(g * 4 + m) * 68 + it * 16 + c] = f2bf(acc[it][m] * 0.015625f);
        LGKM0;
        int trow = lane >> 2, seg = (lane & 3) * 16;
        short8v o0 = *(const short8v*)(&sbw[trow * 68 + seg]);
        short8v o1 = *(const short8v*)(&sbw[trow * 68 + seg + 8]);
        short* dst = G + (((size_t)(n * TT + t0 + trow)) * TT + r) * 64 + seg;
        *(short8v*)dst = o0;
        *(short8v*)(dst + 8) = o1;
    }
}

// ---------- fused cubic attention: barrier-free, complementary-rt pairing -----
// grid 512: n=bid&7 (XCD affinity), rtpair=(bid>>3)&7, tq=bid>>6 (0..7).
// Block handles rt_a=rtpair AND rt_b=15-rtpair sequentially -> per-block work
// proportional to (rt_a+1)+(rt_b+1)=17 (uniform). 8 waves; wave wv handles
// t in {tq+8wv+64k}. U tiles computed in-register by the consuming wave.
// (R16's Ab-prefetch reverted: +20 VGPR cost more occupancy than it saved.)
__global__ __launch_bounds__(512) void attn_kernel(
    const short* __restrict__ K1b, const short* __restrict__ V1b,
    const short* __restrict__ Gm, const short* __restrict__ Ab,
    float* __restrict__ num, float* __restrict__ den)
{
    int bid = blockIdx.x;
    int n = bid & 7;
    int rt_a = (bid >> 3) & 7;
    int rt_b = 15 - rt_a;
    int tq = bid >> 6;            // 0..7
    int tid = threadIdx.x;
    int wv = tid >> 6, lane = tid & 63, g = lane >> 4, c = lane & 15;

    __shared__ short k1lds[256 * 72];   // 36.9 KB
    __shared__ short v1lds[256 * 72];   // 36.9 KB

    int rows = (rt_b + 1) * 16;         // rt_b >= rt_a; covers both phases
    if (rows > 256) rows = 256;

    for (int idx = tid; idx < rows * 8; idx += 512) {
        int row = idx >> 3, seg = idx & 7;
        *(short8v*)(&k1lds[row * 72 + seg * 8]) =
            *(const short8v*)(K1b + ((size_t)n * TT + row) * 64 + seg * 8);
        *(short8v*)(&v1lds[row * 72 + seg * 8]) =
            *(const short8v*)(V1b + ((size_t)n * TT + row) * 64 + seg * 8);
    }
    __syncthreads();   // the only barrier

    #pragma unroll
    for (int phase = 0; phase < 2; ++phase) {
        int rt = phase ? rt_b : rt_a;
        int tmax = rt * 16 + 14;
        if (tmax > 254) tmax = 254;
        int r = rt * 16 + c;

        f32x4 numacc[4];
        #pragma unroll
        for (int b = 0; b < 4; ++b) numacc[b] = (f32x4){0.f, 0.f, 0.f, 0.f};
        float denacc = 0.f;

        for (int t = tq + 8 * wv; t <= tmax; t += 64) {
            if (t < 1) continue;
            int cntU = ((t - 1) >> 4) + 1;  // 1..16 s-tiles

            short8v ab0[4], ab1[4];
            #pragma unroll
            for (int hs = 0; hs < 4; ++hs) {
                const short* ar = Ab + (size_t)(n * TT + t) * 4096 + (hs * 16 + c) * 64 + g * 8;
                ab0[hs] = *(const short8v*)ar;
                ab1[hs] = *(const short8v*)(ar + 32);
            }
            const short* gb = Gm + (((size_t)(n * TT + t) * TT) + rt * 16 + c) * 64 + g * 8;
            short8v gf0 = *(const short8v*)gb;
            short8v gf1 = *(const short8v*)(gb + 32);

            for (int loc = 0; loc < cntU; ++loc) {
                const short* vr = &v1lds[(loc * 16 + c) * 72 + g * 8];
                short8v vf0 = *(const short8v*)vr;
                short8v vf1 = *(const short8v*)(vr + 32);
                short4v ub[4];
                #pragma unroll
                for (int hs = 0; hs < 4; ++hs) {
                    f32x4 u = (f32x4){0.f, 0.f, 0.f, 0.f};
                    u = __builtin_amdgcn_mfma_f32_16x16x32_bf16(vf0, ab0[hs], u, 0, 0, 0);
                    u = __builtin_amdgcn_mfma_f32_16x16x32_bf16(vf1, ab1[hs], u, 0, 0, 0);
                    #pragma unroll
                    for (int m = 0; m < 4; ++m) ub[hs][m] = f2bf(u[m]);
                }
                const short* kr = &k1lds[(loc * 16 + c) * 72 + g * 8];
                short8v af0 = *(const short8v*)kr;
                short8v af1 = *(const short8v*)(kr + 32);
                f32x4 lg = (f32x4){0.f, 0.f, 0.f, 0.f};
                lg = __builtin_amdgcn_mfma_f32_16x16x32_bf16(af0, gf0, lg, 0, 0, 0);
                lg = __builtin_amdgcn_mfma_f32_16x16x32_bf16(af1, gf1, lg, 0, 0, 0);
                int s_base = loc * 16;
                short4v eb;
                float dsum = 0.f;
                #pragma unroll
                for (int m = 0; m < 4; ++m) {
                    int s = s_base + g * 4 + m;
                    float e = (s < t && r > t) ? __expf(lg[m]) : 0.f;   // G pre-scaled 1/64
                    dsum += e;
                    eb[m] = f2bf(e);
                }
                denacc += dsum;
                #pragma unroll
                for (int hs = 0; hs < 4; ++hs)
                    numacc[hs] = __builtin_amdgcn_mfma_f32_16x16x16bf16_1k(eb, ub[hs], numacc[hs], 0, 0, 0);
            }
        }

        // epilogue for this rt
        if (__any(denacc != 0.f)) {
            float v = denacc;
            v += __shfl_xor(v, 16);
            v += __shfl_xor(v, 32);
            if (lane < 16) atomicAdd(&den[n * TT + rt * 16 + lane], v);
            #pragma unroll
            for (int hs = 0; hs < 4; ++hs)
                #pragma unroll
                for (int m = 0; m < 4; ++m)
                    atomicAdd(&num[((size_t)(n * TT + rt * 16 + g * 4 + m)) * 64 + hs * 16 + c],
                              numacc[hs][m]);
        }
    }
}

// ---------- out[t][d] = b_O[d] + (num/den)[t][:] . WOb[d][:]  (fused zdiv) -----
// grid 64: mt=bid&15, dq=bid>>4 (0..3); each wave owns one d-tile.
__global__ __launch_bounds__(512) void out_kernel(const float* __restrict__ num,
                                                  const float* __restrict__ den,
                                                  const short* __restrict__ WOb,
                                                  const float* __restrict__ bO,
                                                  float* __restrict__ out) {
    int mt = blockIdx.x & 15, dq = blockIdx.x >> 4;
    int wv = threadIdx.x >> 6, lane = threadIdx.x & 63, g = lane >> 4, c = lane & 15;
    int dt = dq * 8 + wv;     // 0..31
    int t = mt * 16 + c;
    f32x4 acc = (f32x4){0.f, 0.f, 0.f, 0.f};
    for (int ks = 0; ks < 16; ++ks) {
        int nh = ks * 32 + g * 8;
        int nn = nh >> 6, h = nh & 63;
        float dv = den[nn * 256 + t];
        float rcp = (dv > 0.f) ? 1.f / dv : 0.f;
        const float* np = num + ((size_t)(nn * 256 + t) * 64 + h);
        float4 f0 = *(const float4*)np;
        float4 f1 = *(const float4*)(np + 4);
        short8v a;
        a[0]=f2bf(f0.x*rcp); a[1]=f2bf(f0.y*rcp); a[2]=f2bf(f0.z*rcp); a[3]=f2bf(f0.w*rcp);
        a[4]=f2bf(f1.x*rcp); a[5]=f2bf(f1.y*rcp); a[6]=f2bf(f1.z*rcp); a[7]=f2bf(f1.w*rcp);
        short8v b = *(const short8v*)(WOb + (size_t)(dt * 16 + c) * 512 + ks * 32 + g * 8);
        acc = __builtin_amdgcn_mfma_f32_16x16x32_bf16(a, b, acc, 0, 0, 0);
    }
    int d = dt * 16 + c;
    float bias = bO[d];
    #pragma unroll
    for (int m = 0; m < 4; ++m)
        out[(size_t)(mt * 16 + g * 4 + m) * 512 + d] = acc[m] + bias;
}

extern "C" void kernel_launch(void* const* d_in, const int* in_sizes, int n_in,
                              void* d_out, int out_size, void* d_ws, size_t ws_size,
                              hipStream_t stream) {
    const float* x    = (const float*)d_in[0];
    const float* W_K1 = (const float*)d_in[1];
    const float* W_K2 = (const float*)d_in[2];
    const float* W_Q  = (const float*)d_in[3];
    const float* W_V1 = (const float*)d_in[4];
    const float* W_V2 = (const float*)d_in[5];
    const float* W_Kq = (const float*)d_in[6];
    const float* W_Vq = (const float*)d_in[7];
    const float* W_O  = (const float*)d_in[8];
    const float* b_K1 = (const float*)d_in[9];
    const float* b_K2 = (const float*)d_in[10];
    const float* b_Q  = (const float*)d_in[11];
    const float* b_V1 = (const float*)d_in[12];
    const float* b_V2 = (const float*)d_in[13];
    const float* b_O  = (const float*)d_in[14];
    float* ws = (float*)d_ws;
    short* sb = (short*)(ws + F_END);
    float* out = (float*)d_out;

    // all converts + num/den zeroing
    prep_kernel<<<1802, 256, 0, stream>>>(x, W_Kq, W_K1, W_K2, W_Q, W_V1, W_V2,
                                          W_Vq, W_O, sb, ws + F_NUM);

    // projections (bf16), 160 blocks
    proj_kernel<<<dim3(5, 8, 4), 256, 0, stream>>>(sb + S_XB, sb + S_WB,
                                                   b_K1, b_K2, b_Q, b_V1, b_V2, sb + S_PB);

    // step1[n][r][ij] and Ab[n][t][hi] in one dispatch
    bgemm_kernel<<<dim3(16, 8, 8), 256, 0, stream>>>(
        sb + S_PB + 2 * PROJ, sb + S_KQB, sb + S_S1B,
        sb + S_PB + 4 * PROJ, sb + S_VQB, sb + S_AB);

    // G in [n][t][r][i], coalesced stores, pre-scaled by 1/64
    gmat_kernel<<<512, 256, 0, stream>>>(sb + S_S1B, sb + S_PB + 1 * PROJ, sb + S_GB);

    // fused cubic attention (barrier-free, complementary-rt pairing)
    attn_kernel<<<512, 512, 0, stream>>>(sb + S_PB, sb + S_PB + 3 * PROJ,
                                         sb + S_GB, sb + S_AB,
                                         ws + F_NUM, ws + F_DEN);

    // output projection with fused zdiv, 64 blocks
    out_kernel<<<64, 512, 0, stream>>>(ws + F_NUM, ws + F_DEN, sb + S_WOB, b_O, out);
}